// Round 5
// baseline (1996.262 us; speedup 1.0000x reference)
//
#include <hip/hip_runtime.h>
#include <cstdint>
#include <cstddef>

// Problem constants (fixed by the reference)
#define NN 50000
#define EE 400000
#define FIN 128
#define HH 3
#define DD 64
#define GG 64
#define PP 64
#define HD 192   // H*D

// Cooperative edge-phase geometry
#define COOP_GRID 256          // == CU count; 1 block/CU forced by LDS size
#define COOP_THREADS 1024      // 16 waves
#define NB 196                 // nodes owned per block (256*196 >= 50000)
#define HALF 98                // nodes per sweep (2 sweeps)
#define NPART 5                // src partitions
#define PN 10000               // nodes per partition (10000*384B = 3.84 MB < 4 MiB L2)
#define PART_BYTES (PN * HD * 2)
#define SLICE (PART_BYTES / 32)   // per-block prefetch slice (32 blocks per XCD)
// LDS: dF[98][192] f32 + acc[98][192] f32 + ml[98][8] f32 = 153,664 B
#define SMEM_FLOATS (2 * HALF * HD + HALF * 8)

__device__ inline float wsum(float v) {
#pragma unroll
    for (int m = 32; m > 0; m >>= 1) v += __shfl_xor(v, m, 64);
    return v;
}

// bf16 <-> f32 (RNE)
__device__ inline float bf2f(unsigned short u) {
    union { unsigned int i; float f; } x; x.i = ((unsigned int)u) << 16; return x.f;
}
__device__ inline unsigned short f2bf(float f) {
    union { float f; unsigned int i; } x; x.f = f;
    unsigned int r = x.i + 0x7FFFu + ((x.i >> 16) & 1u);
    return (unsigned short)(r >> 16);
}

// ---------------- CSR build ----------------
__global__ void k_count(const int* __restrict__ dst, int* __restrict__ counts) {
    int e = blockIdx.x * 256 + threadIdx.x;
    if (e < EE) atomicAdd(&counts[dst[e]], 1);
}

__global__ void k_scan_block(const int* __restrict__ in, int* __restrict__ out,
                             int* __restrict__ bsums) {
    __shared__ int tmp[1024];
    int tid = threadIdx.x;
    int i = blockIdx.x * 1024 + tid;
    int v = (i < NN) ? in[i] : 0;
    tmp[tid] = v;
    __syncthreads();
    for (int off = 1; off < 1024; off <<= 1) {
        int t = (tid >= off) ? tmp[tid - off] : 0;
        __syncthreads();
        tmp[tid] += t;
        __syncthreads();
    }
    if (i < NN) out[i] = tmp[tid] - v;       // exclusive within block
    if (tid == 1023) bsums[blockIdx.x] = tmp[1023];
}

__global__ void k_scan_top(int* bsums, int nb) {
    int lane = threadIdx.x;
    int v = (lane < nb) ? bsums[lane] : 0;
    int x = v;
    for (int off = 1; off < 64; off <<= 1) {
        int t = __shfl_up(x, off, 64);
        if (lane >= off) x += t;
    }
    if (lane < nb) bsums[lane] = x - v;      // exclusive
}

__global__ void k_scan_add(int* __restrict__ row_ptr, const int* __restrict__ bsums) {
    int i = blockIdx.x * 1024 + threadIdx.x;
    if (i < NN) row_ptr[i] += bsums[blockIdx.x];
    if (blockIdx.x == 0 && threadIdx.x == 0) row_ptr[NN] = EE;
}

__global__ void k_scatter(const int* __restrict__ src, const int* __restrict__ dst,
                          const int* __restrict__ row_ptr, int* __restrict__ cursor,
                          int* __restrict__ csr_src) {
    int e = blockIdx.x * 256 + threadIdx.x;
    if (e >= EE) return;
    int v = dst[e];
    int pos = row_ptr[v] + atomicAdd(&cursor[v], 1);
    csr_src[pos] = src[e];
}

// ---------------- fs/fd GEMM: [N,K] @ [K,192] x2; FS stored bf16 ----------------
template <int K>
__global__ __launch_bounds__(256) void k_gemm_dual(const float* __restrict__ X,
                                                   const float* __restrict__ Ws,
                                                   const float* __restrict__ Wd,
                                                   unsigned short* __restrict__ FS,
                                                   float* __restrict__ FD) {
    __shared__ float xs[16][K];
    int tid = threadIdx.x;
    int row0 = blockIdx.x * 16;
    for (int idx = tid; idx < 16 * K; idx += 256) {
        int r = idx / K, k = idx - r * K;
        int row = row0 + r;
        xs[r][k] = (row < NN) ? X[(size_t)row * K + k] : 0.f;
    }
    __syncthreads();
    int tx = tid & 63;
    int ty = tid >> 6;
    float acc[4][6];
#pragma unroll
    for (int i = 0; i < 4; i++)
#pragma unroll
        for (int j = 0; j < 6; j++) acc[i][j] = 0.f;

    for (int k = 0; k < K; k++) {
        float w0 = Ws[k * HD + tx];
        float w1 = Ws[k * HD + tx + 64];
        float w2 = Ws[k * HD + tx + 128];
        float w3 = Wd[k * HD + tx];
        float w4 = Wd[k * HD + tx + 64];
        float w5 = Wd[k * HD + tx + 128];
#pragma unroll
        for (int i = 0; i < 4; i++) {
            float x = xs[ty * 4 + i][k];
            acc[i][0] += x * w0; acc[i][1] += x * w1; acc[i][2] += x * w2;
            acc[i][3] += x * w3; acc[i][4] += x * w4; acc[i][5] += x * w5;
        }
    }
#pragma unroll
    for (int i = 0; i < 4; i++) {
        int row = row0 + ty * 4 + i;
        if (row < NN) {
            size_t b = (size_t)row * HD;
            FS[b + tx] = f2bf(acc[i][0]);
            FS[b + tx + 64] = f2bf(acc[i][1]);
            FS[b + tx + 128] = f2bf(acc[i][2]);
            FD[b + tx] = acc[i][3]; FD[b + tx + 64] = acc[i][4]; FD[b + tx + 128] = acc[i][5];
        }
    }
}

// ---------------- grid barrier (perf-only; bounded spin => no deadlock) --------
__device__ inline void gridbar(int* cnt, int* expected) {
    *expected += (int)gridDim.x;
    __syncthreads();
    if (threadIdx.x == 0) {
        atomicAdd(cnt, 1);
        int it = 0;
        while (atomicAdd(cnt, 0) < *expected && it < 300000) {
            __builtin_amdgcn_s_sleep(2);
            it++;
        }
    }
    __syncthreads();
}

// ---------------- cooperative partitioned GATv2 edge phase --------------------
// Persistent: 256 blocks (1/CU), each owns 196 contiguous nodes (2 sweeps x 98).
// For each of 5 src-partitions (3.84 MB bf16 -> fits every XCD's L2): prefetch
// partition into local XCD L2 (sequential), grid barrier, then process edges
// whose src is in-partition (online softmax state in LDS, fp32).
template <bool FINAL>
__global__ __launch_bounds__(COOP_THREADS, 4) void k_gat_coop(
        const int* __restrict__ row_ptr, const int* __restrict__ csr_src,
        const unsigned short* __restrict__ FS, const float* __restrict__ FD,
        const float* __restrict__ A, const float* __restrict__ bias,
        float* __restrict__ OUT, const int* __restrict__ graph_ids,
        float* __restrict__ gsum, int* __restrict__ gcnt,
        int* __restrict__ barc, int* __restrict__ scratch) {
    extern __shared__ float sm[];
    float* dF   = sm;                      // [HALF][192]
    float* accS = sm + HALF * HD;          // [HALF][192]
    float* mlS  = sm + 2 * HALF * HD;      // [HALF][8]: m0..m2 @0..2, l0..l2 @4..6
    int tid = threadIdx.x;
    int lane = tid & 63;
    int wv = tid >> 6;                     // 0..15
    int nb0 = blockIdx.x * NB;
    int expected = 0;

    float a0 = A[lane], a1 = A[64 + lane], a2 = A[128 + lane];

    for (int s = 0; s < 2; s++) {
        int gbase = nb0 + s * HALF;
        int cnt = NN - gbase;
        if (cnt > HALF) cnt = HALF;
        if (cnt < 0) cnt = 0;
        // init LDS state (fd rows stream contiguously)
        for (int idx = tid; idx < cnt * HD; idx += COOP_THREADS) {
            dF[idx] = FD[(size_t)gbase * HD + idx];
            accS[idx] = 0.f;
        }
        for (int idx = tid; idx < cnt * 8; idx += COOP_THREADS)
            mlS[idx] = ((idx & 7) < 4) ? -1e30f : 0.f;
        __syncthreads();

        for (int p = 0; p < NPART; p++) {
            gridbar(barc, &expected);
            // --- prefetch partition p into this XCD's L2 (rank = blockIdx>>3) ---
            {
                const uint4* srcp = (const uint4*)((const char*)FS +
                                     (size_t)p * PART_BYTES + (size_t)(blockIdx.x >> 3) * SLICE);
                unsigned keep = 0;
                for (int i = tid; i < SLICE / 16; i += COOP_THREADS) {
                    uint4 v = srcp[i];
                    keep ^= v.x ^ v.y ^ v.z ^ v.w;
                }
                if (keep == 0x13371337u) scratch[0] = tid;  // keep loads alive
            }
            gridbar(barc, &expected);
            // --- process: wave per node, edges filtered to src in partition ---
            int plo = p * PN;
            for (int n = wv; n < cnt; n += 16) {
                int v = gbase + n;
                int e_s = row_ptr[v], e_e = row_ptr[v + 1];
                float d0 = dF[n * HD + lane];
                float d1 = dF[n * HD + 64 + lane];
                float d2 = dF[n * HD + 128 + lane];
                int n8 = n * 8;
                for (int base = e_s; base < e_e; base += 64) {
                    int ei = base + lane;
                    int uu = (ei < e_e) ? csr_src[ei] : -1;
                    bool ok = (ei < e_e) && ((unsigned)(uu - plo) < (unsigned)PN);
                    unsigned long long mask = __ballot(ok);
                    while (mask) {
                        int b = __builtin_ctzll(mask);
                        mask &= mask - 1;
                        int u = __shfl(uu, b, 64);
                        size_t bu = (size_t)u * HD;
                        float f0 = bf2f(FS[bu + lane]);
                        float f1 = bf2f(FS[bu + 64 + lane]);
                        float f2 = bf2f(FS[bu + 128 + lane]);
                        float s0 = f0 + d0; s0 = s0 > 0.f ? s0 : 0.2f * s0;
                        float s1 = f1 + d1; s1 = s1 > 0.f ? s1 : 0.2f * s1;
                        float s2 = f2 + d2; s2 = s2 > 0.f ? s2 : 0.2f * s2;
                        float lg0 = wsum(s0 * a0);
                        float lg1 = wsum(s1 * a1);
                        float lg2 = wsum(s2 * a2);
                        // online-softmax merge, head 0
                        {
                            float mo = mlS[n8 + 0];
                            float mn = fmaxf(mo, lg0);
                            float sc = __expf(mo - mn);
                            float w  = __expf(lg0 - mn);
                            int ai = n * HD + lane;
                            accS[ai] = accS[ai] * sc + w * f0;
                            if (lane == 0) { mlS[n8 + 0] = mn; mlS[n8 + 4] = mlS[n8 + 4] * sc + w; }
                        }
                        {
                            float mo = mlS[n8 + 1];
                            float mn = fmaxf(mo, lg1);
                            float sc = __expf(mo - mn);
                            float w  = __expf(lg1 - mn);
                            int ai = n * HD + 64 + lane;
                            accS[ai] = accS[ai] * sc + w * f1;
                            if (lane == 0) { mlS[n8 + 1] = mn; mlS[n8 + 5] = mlS[n8 + 5] * sc + w; }
                        }
                        {
                            float mo = mlS[n8 + 2];
                            float mn = fmaxf(mo, lg2);
                            float sc = __expf(mo - mn);
                            float w  = __expf(lg2 - mn);
                            int ai = n * HD + 128 + lane;
                            accS[ai] = accS[ai] * sc + w * f2;
                            if (lane == 0) { mlS[n8 + 2] = mn; mlS[n8 + 6] = mlS[n8 + 6] * sc + w; }
                        }
                    }
                }
            }
        }
        __syncthreads();
        // --- finalize this sweep's nodes ---
        if (!FINAL) {
            for (int idx = tid; idx < cnt * HD; idx += COOP_THREADS) {
                int n = idx / HD; int f = idx - n * HD; int h = f >> 6;
                float l = mlS[n * 8 + 4 + h];
                OUT[(size_t)(gbase + n) * HD + f] = accS[idx] / fmaxf(l, 1e-9f) + bias[f];
            }
        } else {
            for (int idx = tid; idx < cnt * 64; idx += COOP_THREADS) {
                int n = idx >> 6, d = idx & 63;
                float r = 0.f;
#pragma unroll
                for (int h = 0; h < 3; h++)
                    r += accS[n * HD + h * 64 + d] / fmaxf(mlS[n * 8 + 4 + h], 1e-9f) + bias[h * 64 + d];
                r *= (1.f / 3.f);
                int g = graph_ids[gbase + n];
                atomicAdd(&gsum[g * 64 + d], r);
                if (d == 0) atomicAdd(&gcnt[g], 1);
            }
        }
        __syncthreads();
    }
}

// ---------------- head: graph mean + pattern branch + classifier ----------------
__global__ __launch_bounds__(256) void k_head(const float* __restrict__ gsum, const int* __restrict__ gcnt,
                                              const float* __restrict__ p1, const float* __restrict__ p2,
                                              const float* __restrict__ p3,
                                              const float* __restrict__ Wex, const float* __restrict__ bex,
                                              const float* __restrict__ Wpat, const float* __restrict__ bpat,
                                              const float* __restrict__ Wc1, const float* __restrict__ bc1,
                                              const float* __restrict__ Wc2, const float* __restrict__ bc2,
                                              const float* __restrict__ Wc3, const float* __restrict__ bc3,
                                              float* __restrict__ out) {
    __shared__ float EX[64 * 96];    // reused for T1 (4096) + T2 (2048)
    __shared__ float XC[64 * 128];
    int tid = threadIdx.x;
    for (int idx = tid; idx < 64 * 96; idx += 256) {
        int g = idx / 96, j = idx - g * 96;
        const float* pp = (j < 32) ? p1 : ((j < 64) ? p2 : p3);
        int jj = j & 31;
        float acc = bex[jj];
        for (int k = 0; k < 64; k++) acc += pp[g * 64 + k] * Wex[k * 32 + jj];
        EX[idx] = acc;
    }
    for (int idx = tid; idx < 64 * 64; idx += 256) {
        int g = idx >> 6, d = idx & 63;
        float c = (float)gcnt[g];
        XC[g * 128 + d] = gsum[idx] / fmaxf(c, 1.f);
    }
    __syncthreads();
    for (int idx = tid; idx < 64 * 64; idx += 256) {
        int g = idx >> 6, j = idx & 63;
        float acc = bpat[j];
        for (int k = 0; k < 96; k++) acc += EX[g * 96 + k] * Wpat[k * 64 + j];
        XC[g * 128 + 64 + j] = acc > 0.f ? acc : 0.01f * acc;
    }
    __syncthreads();
    float* T1 = EX;
    for (int idx = tid; idx < 64 * 64; idx += 256) {
        int g = idx >> 6, j = idx & 63;
        float acc = bc1[j];
        for (int k = 0; k < 128; k++) acc += XC[g * 128 + k] * Wc1[k * 64 + j];
        T1[idx] = acc > 0.f ? acc : 0.01f * acc;
    }
    __syncthreads();
    float* T2 = EX + 4096;
    for (int idx = tid; idx < 64 * 32; idx += 256) {
        int g = idx >> 5, j = idx & 31;
        float acc = bc2[j];
        for (int k = 0; k < 64; k++) acc += T1[g * 64 + k] * Wc2[k * 32 + j];
        T2[idx] = acc > 0.f ? acc : 0.01f * acc;
    }
    __syncthreads();
    for (int idx = tid; idx < 64 * 2; idx += 256) {
        int g = idx >> 1, c = idx & 1;
        float acc = bc3[c];
        for (int k = 0; k < 32; k++) acc += T2[g * 32 + k] * Wc3[k * 2 + c];
        out[idx] = acc;
    }
}

extern "C" void kernel_launch(void* const* d_in, const int* in_sizes, int n_in,
                              void* d_out, int out_size, void* d_ws, size_t ws_size,
                              hipStream_t stream) {
    const float* X0  = (const float*)d_in[0];
    const int*   src = (const int*)d_in[1];
    const int*   dst = (const int*)d_in[2];
    const int*   gid = (const int*)d_in[3];
    const float* p1  = (const float*)d_in[4];
    const float* p2  = (const float*)d_in[5];
    const float* p3  = (const float*)d_in[6];
    const float* W1s = (const float*)d_in[7],  *W1d = (const float*)d_in[8];
    const float* a1  = (const float*)d_in[9],  *b1  = (const float*)d_in[10];
    const float* W2s = (const float*)d_in[11], *W2d = (const float*)d_in[12];
    const float* a2  = (const float*)d_in[13], *b2  = (const float*)d_in[14];
    const float* W3s = (const float*)d_in[15], *W3d = (const float*)d_in[16];
    const float* a3  = (const float*)d_in[17], *b3  = (const float*)d_in[18];
    const float* Wex = (const float*)d_in[19], *bex = (const float*)d_in[20];
    const float* Wpat= (const float*)d_in[21], *bpat= (const float*)d_in[22];
    const float* Wc1 = (const float*)d_in[23], *bc1 = (const float*)d_in[24];
    const float* Wc2 = (const float*)d_in[25], *bc2 = (const float*)d_in[26];
    const float* Wc3 = (const float*)d_in[27], *bc3 = (const float*)d_in[28];
    float* out = (float*)d_out;

    char* ws = (char*)d_ws;
    size_t off = 0;
    auto alloc = [&](size_t bytes) -> char* {
        char* p = ws + off;
        off = (off + bytes + 255) & ~(size_t)255;
        return p;
    };
    unsigned short* FS = (unsigned short*)alloc((size_t)NN * HD * 2);  // bf16
    float* FD = (float*)alloc((size_t)NN * HD * 4);
    float* HA = (float*)alloc((size_t)NN * HD * 4);
    float* HB = (float*)alloc((size_t)NN * HD * 4);
    int* row_ptr = (int*)alloc((size_t)(NN + 1) * 4);
    int* csr_src = (int*)alloc((size_t)EE * 4);
    int* bsums   = (int*)alloc(64 * 4);
    // zeroed region (one memset): counts | cursor | gsum | gcnt | barriers
    char* zbase = ws + off;
    int*   counts = (int*)alloc((size_t)NN * 4);
    int*   cursor = (int*)alloc((size_t)NN * 4);
    float* gsum   = (float*)alloc((size_t)GG * 64 * 4);
    int*   gcnt   = (int*)alloc((size_t)GG * 4);
    int*   barr   = (int*)alloc(16 * 4);   // [0..2]: per-layer counters, [8]: scratch
    size_t zbytes = (size_t)((ws + off) - zbase);

    hipMemsetAsync(zbase, 0, zbytes, stream);

    // opt-in to >64KB dynamic LDS (host-side, idempotent)
    {
        auto* f0 = k_gat_coop<false>;
        auto* f1 = k_gat_coop<true>;
        hipFuncSetAttribute((const void*)f0, hipFuncAttributeMaxDynamicSharedMemorySize,
                            SMEM_FLOATS * 4);
        hipFuncSetAttribute((const void*)f1, hipFuncAttributeMaxDynamicSharedMemorySize,
                            SMEM_FLOATS * 4);
    }

    int ebl = (EE + 255) / 256;
    int nb  = (NN + 1023) / 1024;
    k_count<<<ebl, 256, 0, stream>>>(dst, counts);
    k_scan_block<<<nb, 1024, 0, stream>>>(counts, row_ptr, bsums);
    k_scan_top<<<1, 64, 0, stream>>>(bsums, nb);
    k_scan_add<<<nb, 1024, 0, stream>>>(row_ptr, bsums);
    k_scatter<<<ebl, 256, 0, stream>>>(src, dst, row_ptr, cursor, csr_src);

    int gblk = (NN + 15) / 16;
    size_t smem = SMEM_FLOATS * 4;

    // layer 1 (K = 128)
    k_gemm_dual<128><<<gblk, 256, 0, stream>>>(X0, W1s, W1d, FS, FD);
    k_gat_coop<false><<<COOP_GRID, COOP_THREADS, smem, stream>>>(
        row_ptr, csr_src, FS, FD, a1, b1, HA, nullptr, nullptr, nullptr, barr + 0, barr + 8);
    // layer 2 (K = 192)
    k_gemm_dual<192><<<gblk, 256, 0, stream>>>(HA, W2s, W2d, FS, FD);
    k_gat_coop<false><<<COOP_GRID, COOP_THREADS, smem, stream>>>(
        row_ptr, csr_src, FS, FD, a2, b2, HB, nullptr, nullptr, nullptr, barr + 1, barr + 8);
    // layer 3 (K = 192), fused head-mean + graph-sum
    k_gemm_dual<192><<<gblk, 256, 0, stream>>>(HB, W3s, W3d, FS, FD);
    k_gat_coop<true><<<COOP_GRID, COOP_THREADS, smem, stream>>>(
        row_ptr, csr_src, FS, FD, a3, b3, nullptr, gid, gsum, gcnt, barr + 2, barr + 8);

    k_head<<<1, 256, 0, stream>>>(gsum, gcnt, p1, p2, p3, Wex, bex, Wpat, bpat,
                                  Wc1, bc1, Wc2, bc2, Wc3, bc3, out);
}

// Round 6
// 1790.150 us; speedup vs baseline: 1.1151x; 1.1151x over previous
//
#include <hip/hip_runtime.h>
#include <cstdint>
#include <cstddef>

// Problem constants (fixed by the reference)
#define NN 50000
#define EE 400000
#define FIN 128
#define HH 3
#define DD 64
#define GG 64
#define PP 64
#define HD 192   // H*D

__device__ inline float wsum(float v) {
#pragma unroll
    for (int m = 32; m > 0; m >>= 1) v += __shfl_xor(v, m, 64);
    return v;
}

// bf16 <-> f32 (RNE)
__device__ inline float bf2f(unsigned short u) {
    union { unsigned int i; float f; } x; x.i = ((unsigned int)u) << 16; return x.f;
}
__device__ inline unsigned short f2bf(float f) {
    union { float f; unsigned int i; } x; x.f = f;
    unsigned int r = x.i + 0x7FFFu + ((x.i >> 16) & 1u);
    return (unsigned short)(r >> 16);
}

// ---------------- fs/fd GEMM: [N,K] @ [K,192] x2; both outputs bf16 ----------------
template <int K>
__global__ __launch_bounds__(256) void k_gemm_dual(const float* __restrict__ X,
                                                   const float* __restrict__ Ws,
                                                   const float* __restrict__ Wd,
                                                   unsigned short* __restrict__ FS,
                                                   unsigned short* __restrict__ FD) {
    __shared__ float xs[16][K];
    int tid = threadIdx.x;
    int row0 = blockIdx.x * 16;
    for (int idx = tid; idx < 16 * K; idx += 256) {
        int r = idx / K, k = idx - r * K;
        int row = row0 + r;
        xs[r][k] = (row < NN) ? X[(size_t)row * K + k] : 0.f;
    }
    __syncthreads();
    int tx = tid & 63;
    int ty = tid >> 6;
    float acc[4][6];
#pragma unroll
    for (int i = 0; i < 4; i++)
#pragma unroll
        for (int j = 0; j < 6; j++) acc[i][j] = 0.f;

    for (int k = 0; k < K; k++) {
        float w0 = Ws[k * HD + tx];
        float w1 = Ws[k * HD + tx + 64];
        float w2 = Ws[k * HD + tx + 128];
        float w3 = Wd[k * HD + tx];
        float w4 = Wd[k * HD + tx + 64];
        float w5 = Wd[k * HD + tx + 128];
#pragma unroll
        for (int i = 0; i < 4; i++) {
            float x = xs[ty * 4 + i][k];
            acc[i][0] += x * w0; acc[i][1] += x * w1; acc[i][2] += x * w2;
            acc[i][3] += x * w3; acc[i][4] += x * w4; acc[i][5] += x * w5;
        }
    }
#pragma unroll
    for (int i = 0; i < 4; i++) {
        int row = row0 + ty * 4 + i;
        if (row < NN) {
            size_t b = (size_t)row * HD;
            FS[b + tx]       = f2bf(acc[i][0]);
            FS[b + tx + 64]  = f2bf(acc[i][1]);
            FS[b + tx + 128] = f2bf(acc[i][2]);
            FD[b + tx]       = f2bf(acc[i][3]);
            FD[b + tx + 64]  = f2bf(acc[i][4]);
            FD[b + tx + 128] = f2bf(acc[i][5]);
        }
    }
}

// ---------------- edge-parallel GATv2: gather + logits + exp + atomic scatter ----
// One wave per 2 edges. No CSR, no segment-max (logits are O(1): exp is safe
// unshifted and mathematically identical after the ratio), no serial chains:
// 12 independent gathers -> 6 independent wsum reductions -> fire-and-forget
// atomics. DEN[v][h] accumulates the softmax denominator.
__global__ __launch_bounds__(256) void k_edge_atomic(const int* __restrict__ src,
                                                     const int* __restrict__ dst,
                                                     const unsigned short* __restrict__ FS,
                                                     const unsigned short* __restrict__ FD,
                                                     const float* __restrict__ A,
                                                     float* __restrict__ ACC,
                                                     float* __restrict__ DEN) {
    int wv = threadIdx.x >> 6, lane = threadIdx.x & 63;
    int e0 = blockIdx.x * 8 + wv * 2;
    bool ok0 = e0 < EE, ok1 = (e0 + 1) < EE;
    float a0 = A[lane], a1 = A[64 + lane], a2 = A[128 + lane];

    int u0 = ok0 ? src[e0] : 0,     v0 = ok0 ? dst[e0] : 0;
    int u1 = ok1 ? src[e0 + 1] : 0, v1 = ok1 ? dst[e0 + 1] : 0;
    size_t bu0 = (size_t)u0 * HD, bv0 = (size_t)v0 * HD;
    size_t bu1 = (size_t)u1 * HD, bv1 = (size_t)v1 * HD;

    // 12 independent gathers (bf16, coalesced 128B each)
    float f00 = bf2f(FS[bu0 + lane]), f01 = bf2f(FS[bu0 + 64 + lane]), f02 = bf2f(FS[bu0 + 128 + lane]);
    float g00 = bf2f(FD[bv0 + lane]), g01 = bf2f(FD[bv0 + 64 + lane]), g02 = bf2f(FD[bv0 + 128 + lane]);
    float f10 = bf2f(FS[bu1 + lane]), f11 = bf2f(FS[bu1 + 64 + lane]), f12 = bf2f(FS[bu1 + 128 + lane]);
    float g10 = bf2f(FD[bv1 + lane]), g11 = bf2f(FD[bv1 + 64 + lane]), g12 = bf2f(FD[bv1 + 128 + lane]);

    float s;
    s = f00 + g00; s = s > 0.f ? s : 0.2f * s; float l00 = s * a0;
    s = f01 + g01; s = s > 0.f ? s : 0.2f * s; float l01 = s * a1;
    s = f02 + g02; s = s > 0.f ? s : 0.2f * s; float l02 = s * a2;
    s = f10 + g10; s = s > 0.f ? s : 0.2f * s; float l10 = s * a0;
    s = f11 + g11; s = s > 0.f ? s : 0.2f * s; float l11 = s * a1;
    s = f12 + g12; s = s > 0.f ? s : 0.2f * s; float l12 = s * a2;

    // 6 independent reductions (compiler interleaves the shuffle chains)
    float lg00 = wsum(l00), lg01 = wsum(l01), lg02 = wsum(l02);
    float lg10 = wsum(l10), lg11 = wsum(l11), lg12 = wsum(l12);

    float w00 = __expf(lg00), w01 = __expf(lg01), w02 = __expf(lg02);
    float w10 = __expf(lg10), w11 = __expf(lg11), w12 = __expf(lg12);

    if (ok0) {
        atomicAdd(&ACC[bv0 + lane],       w00 * f00);
        atomicAdd(&ACC[bv0 + 64 + lane],  w01 * f01);
        atomicAdd(&ACC[bv0 + 128 + lane], w02 * f02);
        if (lane < 3) {
            float dv = lane == 0 ? w00 : (lane == 1 ? w01 : w02);
            atomicAdd(&DEN[v0 * 4 + lane], dv);
        }
    }
    if (ok1) {
        atomicAdd(&ACC[bv1 + lane],       w10 * f10);
        atomicAdd(&ACC[bv1 + 64 + lane],  w11 * f11);
        atomicAdd(&ACC[bv1 + 128 + lane], w12 * f12);
        if (lane < 3) {
            float dv = lane == 0 ? w10 : (lane == 1 ? w11 : w12);
            atomicAdd(&DEN[v1 * 4 + lane], dv);
        }
    }
}

// ---------------- finalize: divide by denom (+bias); final layer adds graph mean --
__global__ __launch_bounds__(256) void k_finalize(const float* __restrict__ ACC,
                                                  const float* __restrict__ DEN,
                                                  const float* __restrict__ bias,
                                                  float* __restrict__ OUT) {
    int idx = blockIdx.x * 256 + threadIdx.x;
    if (idx >= NN * HD) return;
    int v = idx / HD;
    int f = idx - v * HD;
    int h = f >> 6;
    float den = DEN[v * 4 + h];
    OUT[idx] = ACC[idx] / fmaxf(den, 1e-9f) + bias[f];
}

__global__ __launch_bounds__(256) void k_finalize_last(const float* __restrict__ ACC,
                                                       const float* __restrict__ DEN,
                                                       const float* __restrict__ bias,
                                                       const int* __restrict__ graph_ids,
                                                       float* __restrict__ gsum,
                                                       int* __restrict__ gcnt) {
    int idx = blockIdx.x * 256 + threadIdx.x;
    if (idx >= NN * 64) return;
    int v = idx >> 6, d = idx & 63;
    float r = 0.f;
#pragma unroll
    for (int h = 0; h < 3; h++) {
        float den = DEN[v * 4 + h];
        r += ACC[(size_t)v * HD + h * 64 + d] / fmaxf(den, 1e-9f) + bias[h * 64 + d];
    }
    r *= (1.f / 3.f);
    int g = graph_ids[v];
    atomicAdd(&gsum[g * 64 + d], r);
    if (d == 0) atomicAdd(&gcnt[g], 1);
}

// ---------------- head: graph mean + pattern branch + classifier ----------------
__global__ __launch_bounds__(256) void k_head(const float* __restrict__ gsum, const int* __restrict__ gcnt,
                                              const float* __restrict__ p1, const float* __restrict__ p2,
                                              const float* __restrict__ p3,
                                              const float* __restrict__ Wex, const float* __restrict__ bex,
                                              const float* __restrict__ Wpat, const float* __restrict__ bpat,
                                              const float* __restrict__ Wc1, const float* __restrict__ bc1,
                                              const float* __restrict__ Wc2, const float* __restrict__ bc2,
                                              const float* __restrict__ Wc3, const float* __restrict__ bc3,
                                              float* __restrict__ out) {
    __shared__ float EX[64 * 96];    // reused for T1 (4096) + T2 (2048)
    __shared__ float XC[64 * 128];
    int tid = threadIdx.x;
    for (int idx = tid; idx < 64 * 96; idx += 256) {
        int g = idx / 96, j = idx - g * 96;
        const float* pp = (j < 32) ? p1 : ((j < 64) ? p2 : p3);
        int jj = j & 31;
        float acc = bex[jj];
        for (int k = 0; k < 64; k++) acc += pp[g * 64 + k] * Wex[k * 32 + jj];
        EX[idx] = acc;
    }
    for (int idx = tid; idx < 64 * 64; idx += 256) {
        int g = idx >> 6, d = idx & 63;
        float c = (float)gcnt[g];
        XC[g * 128 + d] = gsum[idx] / fmaxf(c, 1.f);
    }
    __syncthreads();
    for (int idx = tid; idx < 64 * 64; idx += 256) {
        int g = idx >> 6, j = idx & 63;
        float acc = bpat[j];
        for (int k = 0; k < 96; k++) acc += EX[g * 96 + k] * Wpat[k * 64 + j];
        XC[g * 128 + 64 + j] = acc > 0.f ? acc : 0.01f * acc;
    }
    __syncthreads();
    float* T1 = EX;
    for (int idx = tid; idx < 64 * 64; idx += 256) {
        int g = idx >> 6, j = idx & 63;
        float acc = bc1[j];
        for (int k = 0; k < 128; k++) acc += XC[g * 128 + k] * Wc1[k * 64 + j];
        T1[idx] = acc > 0.f ? acc : 0.01f * acc;
    }
    __syncthreads();
    float* T2 = EX + 4096;
    for (int idx = tid; idx < 64 * 32; idx += 256) {
        int g = idx >> 5, j = idx & 31;
        float acc = bc2[j];
        for (int k = 0; k < 64; k++) acc += T1[g * 64 + k] * Wc2[k * 32 + j];
        T2[idx] = acc > 0.f ? acc : 0.01f * acc;
    }
    __syncthreads();
    for (int idx = tid; idx < 64 * 2; idx += 256) {
        int g = idx >> 1, c = idx & 1;
        float acc = bc3[c];
        for (int k = 0; k < 32; k++) acc += T2[g * 32 + k] * Wc3[k * 2 + c];
        out[idx] = acc;
    }
}

extern "C" void kernel_launch(void* const* d_in, const int* in_sizes, int n_in,
                              void* d_out, int out_size, void* d_ws, size_t ws_size,
                              hipStream_t stream) {
    const float* X0  = (const float*)d_in[0];
    const int*   src = (const int*)d_in[1];
    const int*   dst = (const int*)d_in[2];
    const int*   gid = (const int*)d_in[3];
    const float* p1  = (const float*)d_in[4];
    const float* p2  = (const float*)d_in[5];
    const float* p3  = (const float*)d_in[6];
    const float* W1s = (const float*)d_in[7],  *W1d = (const float*)d_in[8];
    const float* a1  = (const float*)d_in[9],  *b1  = (const float*)d_in[10];
    const float* W2s = (const float*)d_in[11], *W2d = (const float*)d_in[12];
    const float* a2  = (const float*)d_in[13], *b2  = (const float*)d_in[14];
    const float* W3s = (const float*)d_in[15], *W3d = (const float*)d_in[16];
    const float* a3  = (const float*)d_in[17], *b3  = (const float*)d_in[18];
    const float* Wex = (const float*)d_in[19], *bex = (const float*)d_in[20];
    const float* Wpat= (const float*)d_in[21], *bpat= (const float*)d_in[22];
    const float* Wc1 = (const float*)d_in[23], *bc1 = (const float*)d_in[24];
    const float* Wc2 = (const float*)d_in[25], *bc2 = (const float*)d_in[26];
    const float* Wc3 = (const float*)d_in[27], *bc3 = (const float*)d_in[28];
    float* out = (float*)d_out;

    char* ws = (char*)d_ws;
    size_t off = 0;
    auto alloc = [&](size_t bytes) -> char* {
        char* p = ws + off;
        off = (off + bytes + 255) & ~(size_t)255;
        return p;
    };
    unsigned short* FS = (unsigned short*)alloc((size_t)NN * HD * 2);  // bf16
    unsigned short* FD = (unsigned short*)alloc((size_t)NN * HD * 2);  // bf16
    float* HA = (float*)alloc((size_t)NN * HD * 4);
    float* HB = (float*)alloc((size_t)NN * HD * 4);
    // ACC + DEN contiguous -> one memset per layer
    float* ACC = (float*)alloc((size_t)NN * HD * 4);
    float* DEN = (float*)alloc((size_t)NN * 4 * 4);
    size_t accden_bytes = (size_t)NN * HD * 4 + (size_t)NN * 4 * 4;
    // zeroed-once region: gsum | gcnt
    char* zbase = ws + off;
    float* gsum = (float*)alloc((size_t)GG * 64 * 4);
    int*   gcnt = (int*)alloc((size_t)GG * 4);
    size_t zbytes = (size_t)((ws + off) - zbase);

    hipMemsetAsync(zbase, 0, zbytes, stream);

    int gblk = (NN + 15) / 16;
    int eblk = (EE + 7) / 8;
    int fblk = (NN * HD + 255) / 256;
    int lblk = (NN * 64 + 255) / 256;

    // layer 1 (K = 128)
    hipMemsetAsync(ACC, 0, accden_bytes, stream);
    k_gemm_dual<128><<<gblk, 256, 0, stream>>>(X0, W1s, W1d, FS, FD);
    k_edge_atomic<<<eblk, 256, 0, stream>>>(src, dst, FS, FD, a1, ACC, DEN);
    k_finalize<<<fblk, 256, 0, stream>>>(ACC, DEN, b1, HA);
    // layer 2 (K = 192)
    hipMemsetAsync(ACC, 0, accden_bytes, stream);
    k_gemm_dual<192><<<gblk, 256, 0, stream>>>(HA, W2s, W2d, FS, FD);
    k_edge_atomic<<<eblk, 256, 0, stream>>>(src, dst, FS, FD, a2, ACC, DEN);
    k_finalize<<<fblk, 256, 0, stream>>>(ACC, DEN, b2, HB);
    // layer 3 (K = 192), finalize fuses head-mean + graph-sum
    hipMemsetAsync(ACC, 0, accden_bytes, stream);
    k_gemm_dual<192><<<gblk, 256, 0, stream>>>(HB, W3s, W3d, FS, FD);
    k_edge_atomic<<<eblk, 256, 0, stream>>>(src, dst, FS, FD, a3, ACC, DEN);
    k_finalize_last<<<lblk, 256, 0, stream>>>(ACC, DEN, b3, gid, gsum, gcnt);

    k_head<<<1, 256, 0, stream>>>(gsum, gcnt, p1, p2, p3, Wex, bex, Wpat, bpat,
                                  Wc1, bc1, Wc2, bc2, Wc3, bc3, out);
}

// Round 7
// 1392.725 us; speedup vs baseline: 1.4333x; 1.2854x over previous
//
#include <hip/hip_runtime.h>
#include <cstdint>
#include <cstddef>

// Problem constants (fixed by the reference)
#define NN 50000
#define EE 400000
#define FIN 128
#define HH 3
#define DD 64
#define GG 64
#define PP 64
#define HD 192   // H*D

__device__ inline float wsum(float v) {
#pragma unroll
    for (int m = 32; m > 0; m >>= 1) v += __shfl_xor(v, m, 64);
    return v;
}

// bf16 <-> f32 (RNE)
__device__ inline float bf2f(unsigned short u) {
    union { unsigned int i; float f; } x; x.i = ((unsigned int)u) << 16; return x.f;
}
__device__ inline unsigned short f2bf(float f) {
    union { float f; unsigned int i; } x; x.f = f;
    unsigned int r = x.i + 0x7FFFu + ((x.i >> 16) & 1u);
    return (unsigned short)(r >> 16);
}

// ---------------- fs/fd GEMM: [N,K] @ [K,192] x2; outputs bf16 -----------------
// FUSE: input row = ACC[row]/DEN[row] + bias_prev (fuses previous layer's
// softmax-normalize epilogue into the staging load; kills k_finalize + H buffer)
template <int K, bool FUSE>
__global__ __launch_bounds__(256) void k_gemm_dual(const float* __restrict__ X,
                                                   const float* __restrict__ DENp,
                                                   const float* __restrict__ bprev,
                                                   const float* __restrict__ Ws,
                                                   const float* __restrict__ Wd,
                                                   unsigned short* __restrict__ FS,
                                                   unsigned short* __restrict__ FD) {
    __shared__ float xs[16][K];
    int tid = threadIdx.x;
    int row0 = blockIdx.x * 16;
    for (int idx = tid; idx < 16 * K; idx += 256) {
        int r = idx / K, k = idx - r * K;
        int row = row0 + r;
        float val = 0.f;
        if (row < NN) {
            if (FUSE) {
                float den = DENp[row * 4 + (k >> 6)];
                val = X[(size_t)row * K + k] / fmaxf(den, 1e-9f) + bprev[k];
            } else {
                val = X[(size_t)row * K + k];
            }
        }
        xs[r][k] = val;
    }
    __syncthreads();
    int tx = tid & 63;
    int ty = tid >> 6;
    float acc[4][6];
#pragma unroll
    for (int i = 0; i < 4; i++)
#pragma unroll
        for (int j = 0; j < 6; j++) acc[i][j] = 0.f;

    for (int k = 0; k < K; k++) {
        float w0 = Ws[k * HD + tx];
        float w1 = Ws[k * HD + tx + 64];
        float w2 = Ws[k * HD + tx + 128];
        float w3 = Wd[k * HD + tx];
        float w4 = Wd[k * HD + tx + 64];
        float w5 = Wd[k * HD + tx + 128];
#pragma unroll
        for (int i = 0; i < 4; i++) {
            float x = xs[ty * 4 + i][k];
            acc[i][0] += x * w0; acc[i][1] += x * w1; acc[i][2] += x * w2;
            acc[i][3] += x * w3; acc[i][4] += x * w4; acc[i][5] += x * w5;
        }
    }
#pragma unroll
    for (int i = 0; i < 4; i++) {
        int row = row0 + ty * 4 + i;
        if (row < NN) {
            size_t b = (size_t)row * HD;
            FS[b + tx]       = f2bf(acc[i][0]);
            FS[b + tx + 64]  = f2bf(acc[i][1]);
            FS[b + tx + 128] = f2bf(acc[i][2]);
            FD[b + tx]       = f2bf(acc[i][3]);
            FD[b + tx + 64]  = f2bf(acc[i][4]);
            FD[b + tx + 128] = f2bf(acc[i][5]);
        }
    }
}

// ---------------- edge-parallel GATv2: gather + logits + exp + atomic scatter ----
// One wave per 4 edges: 24 independent gathers in flight, 12 interleaved
// shuffle-reductions, fire-and-forget atomics. No CSR, no segment-max (logits
// are O(1) here; unshifted exp is exact after the ratio).
__global__ __launch_bounds__(256) void k_edge_atomic(const int* __restrict__ src,
                                                     const int* __restrict__ dst,
                                                     const unsigned short* __restrict__ FS,
                                                     const unsigned short* __restrict__ FD,
                                                     const float* __restrict__ A,
                                                     float* __restrict__ ACC,
                                                     float* __restrict__ DEN) {
    int wv = threadIdx.x >> 6, lane = threadIdx.x & 63;
    int e0 = blockIdx.x * 16 + wv * 4;
    float a0 = A[lane], a1 = A[64 + lane], a2 = A[128 + lane];

    int u[4], v[4];
    bool ok[4];
#pragma unroll
    for (int i = 0; i < 4; i++) {
        int e = e0 + i;
        ok[i] = e < EE;
        u[i] = ok[i] ? src[e] : 0;
        v[i] = ok[i] ? dst[e] : 0;
    }
    float f[4][3], g[4][3];
#pragma unroll
    for (int i = 0; i < 4; i++) {
        size_t bu = (size_t)u[i] * HD, bv = (size_t)v[i] * HD;
        f[i][0] = bf2f(FS[bu + lane]);
        f[i][1] = bf2f(FS[bu + 64 + lane]);
        f[i][2] = bf2f(FS[bu + 128 + lane]);
        g[i][0] = bf2f(FD[bv + lane]);
        g[i][1] = bf2f(FD[bv + 64 + lane]);
        g[i][2] = bf2f(FD[bv + 128 + lane]);
    }
    float w[4][3];
#pragma unroll
    for (int i = 0; i < 4; i++) {
        float s0 = f[i][0] + g[i][0]; s0 = s0 > 0.f ? s0 : 0.2f * s0;
        float s1 = f[i][1] + g[i][1]; s1 = s1 > 0.f ? s1 : 0.2f * s1;
        float s2 = f[i][2] + g[i][2]; s2 = s2 > 0.f ? s2 : 0.2f * s2;
        w[i][0] = s0 * a0; w[i][1] = s1 * a1; w[i][2] = s2 * a2;
    }
#pragma unroll
    for (int i = 0; i < 4; i++) {
#pragma unroll
        for (int h = 0; h < 3; h++) w[i][h] = wsum(w[i][h]);
    }
#pragma unroll
    for (int i = 0; i < 4; i++) {
#pragma unroll
        for (int h = 0; h < 3; h++) w[i][h] = __expf(w[i][h]);
    }
#pragma unroll
    for (int i = 0; i < 4; i++) {
        if (ok[i]) {
            size_t bv = (size_t)v[i] * HD;
            atomicAdd(&ACC[bv + lane],       w[i][0] * f[i][0]);
            atomicAdd(&ACC[bv + 64 + lane],  w[i][1] * f[i][1]);
            atomicAdd(&ACC[bv + 128 + lane], w[i][2] * f[i][2]);
            if (lane < 3) atomicAdd(&DEN[v[i] * 4 + lane], w[i][lane]);
        }
    }
}

// ---------------- final: per-graph mean (graph_ids SORTED -> binary search) -----
// 4 blocks per graph; block-local reduce; 64 atomics/block (vs 3.2M before).
__global__ __launch_bounds__(256) void k_graph_mean(const float* __restrict__ ACC,
                                                    const float* __restrict__ DEN,
                                                    const float* __restrict__ bias,
                                                    const int* __restrict__ gids,
                                                    float* __restrict__ gsum,
                                                    int* __restrict__ gcnt) {
    int g = blockIdx.x >> 2, q = blockIdx.x & 3;
    int lo, hi;
    {
        int a = 0, b = NN;
        while (a < b) { int m = (a + b) >> 1; if (gids[m] < g) a = m + 1; else b = m; }
        lo = a;
        b = NN;
        while (a < b) { int m = (a + b) >> 1; if (gids[m] < g + 1) a = m + 1; else b = m; }
        hi = a;
    }
    int len = hi - lo;
    int qlen = (len + 3) >> 2;
    int s = lo + q * qlen;
    int e = s + qlen; if (e > hi) e = hi;
    int lane = threadIdx.x & 63, wv = threadIdx.x >> 6;

    float acc = 0.f;
    for (int v = s + wv; v < e; v += 4) {
        float r = 0.f;
#pragma unroll
        for (int h = 0; h < 3; h++) {
            float den = DEN[v * 4 + h];
            r += ACC[(size_t)v * HD + h * 64 + lane] / fmaxf(den, 1e-9f) + bias[h * 64 + lane];
        }
        acc += r * (1.f / 3.f);
    }
    __shared__ float red[4][64];
    red[wv][lane] = acc;
    __syncthreads();
    if (wv == 0) {
        float t = red[0][lane] + red[1][lane] + red[2][lane] + red[3][lane];
        if (e > s) {
            atomicAdd(&gsum[g * 64 + lane], t);
            if (lane == 0) atomicAdd(&gcnt[g], e - s);
        }
    }
}

// ---------------- head: graph mean + pattern branch + classifier ----------------
__global__ __launch_bounds__(256) void k_head(const float* __restrict__ gsum, const int* __restrict__ gcnt,
                                              const float* __restrict__ p1, const float* __restrict__ p2,
                                              const float* __restrict__ p3,
                                              const float* __restrict__ Wex, const float* __restrict__ bex,
                                              const float* __restrict__ Wpat, const float* __restrict__ bpat,
                                              const float* __restrict__ Wc1, const float* __restrict__ bc1,
                                              const float* __restrict__ Wc2, const float* __restrict__ bc2,
                                              const float* __restrict__ Wc3, const float* __restrict__ bc3,
                                              float* __restrict__ out) {
    __shared__ float EX[64 * 96];    // reused for T1 (4096) + T2 (2048)
    __shared__ float XC[64 * 128];
    int tid = threadIdx.x;
    for (int idx = tid; idx < 64 * 96; idx += 256) {
        int g = idx / 96, j = idx - g * 96;
        const float* pp = (j < 32) ? p1 : ((j < 64) ? p2 : p3);
        int jj = j & 31;
        float acc = bex[jj];
        for (int k = 0; k < 64; k++) acc += pp[g * 64 + k] * Wex[k * 32 + jj];
        EX[idx] = acc;
    }
    for (int idx = tid; idx < 64 * 64; idx += 256) {
        int g = idx >> 6, d = idx & 63;
        float c = (float)gcnt[g];
        XC[g * 128 + d] = gsum[idx] / fmaxf(c, 1.f);
    }
    __syncthreads();
    for (int idx = tid; idx < 64 * 64; idx += 256) {
        int g = idx >> 6, j = idx & 63;
        float acc = bpat[j];
        for (int k = 0; k < 96; k++) acc += EX[g * 96 + k] * Wpat[k * 64 + j];
        XC[g * 128 + 64 + j] = acc > 0.f ? acc : 0.01f * acc;
    }
    __syncthreads();
    float* T1 = EX;
    for (int idx = tid; idx < 64 * 64; idx += 256) {
        int g = idx >> 6, j = idx & 63;
        float acc = bc1[j];
        for (int k = 0; k < 128; k++) acc += XC[g * 128 + k] * Wc1[k * 64 + j];
        T1[idx] = acc > 0.f ? acc : 0.01f * acc;
    }
    __syncthreads();
    float* T2 = EX + 4096;
    for (int idx = tid; idx < 64 * 32; idx += 256) {
        int g = idx >> 5, j = idx & 31;
        float acc = bc2[j];
        for (int k = 0; k < 64; k++) acc += T1[g * 64 + k] * Wc2[k * 32 + j];
        T2[idx] = acc > 0.f ? acc : 0.01f * acc;
    }
    __syncthreads();
    for (int idx = tid; idx < 64 * 2; idx += 256) {
        int g = idx >> 1, c = idx & 1;
        float acc = bc3[c];
        for (int k = 0; k < 32; k++) acc += T2[g * 32 + k] * Wc3[k * 2 + c];
        out[idx] = acc;
    }
}

extern "C" void kernel_launch(void* const* d_in, const int* in_sizes, int n_in,
                              void* d_out, int out_size, void* d_ws, size_t ws_size,
                              hipStream_t stream) {
    const float* X0  = (const float*)d_in[0];
    const int*   src = (const int*)d_in[1];
    const int*   dst = (const int*)d_in[2];
    const int*   gid = (const int*)d_in[3];
    const float* p1  = (const float*)d_in[4];
    const float* p2  = (const float*)d_in[5];
    const float* p3  = (const float*)d_in[6];
    const float* W1s = (const float*)d_in[7],  *W1d = (const float*)d_in[8];
    const float* a1  = (const float*)d_in[9],  *b1  = (const float*)d_in[10];
    const float* W2s = (const float*)d_in[11], *W2d = (const float*)d_in[12];
    const float* a2  = (const float*)d_in[13], *b2  = (const float*)d_in[14];
    const float* W3s = (const float*)d_in[15], *W3d = (const float*)d_in[16];
    const float* a3  = (const float*)d_in[17], *b3  = (const float*)d_in[18];
    const float* Wex = (const float*)d_in[19], *bex = (const float*)d_in[20];
    const float* Wpat= (const float*)d_in[21], *bpat= (const float*)d_in[22];
    const float* Wc1 = (const float*)d_in[23], *bc1 = (const float*)d_in[24];
    const float* Wc2 = (const float*)d_in[25], *bc2 = (const float*)d_in[26];
    const float* Wc3 = (const float*)d_in[27], *bc3 = (const float*)d_in[28];
    float* out = (float*)d_out;

    char* ws = (char*)d_ws;
    size_t off = 0;
    auto alloc = [&](size_t bytes) -> char* {
        char* p = ws + off;
        off = (off + bytes + 255) & ~(size_t)255;
        return p;
    };
    unsigned short* FS = (unsigned short*)alloc((size_t)NN * HD * 2);  // bf16
    unsigned short* FD = (unsigned short*)alloc((size_t)NN * HD * 2);  // bf16
    // two ACC/DEN ping-pong buffers; each ACC|DEN contiguous -> one memset
    float* ACCa = (float*)alloc((size_t)NN * HD * 4);
    float* DENa = (float*)alloc((size_t)NN * 4 * 4);
    float* ACCb = (float*)alloc((size_t)NN * HD * 4);
    float* DENb = (float*)alloc((size_t)NN * 4 * 4);
    size_t accden_bytes = (size_t)((char*)DENa - (char*)ACCa) + (size_t)NN * 4 * 4;
    // zeroed-once region: gsum | gcnt
    char* zbase = ws + off;
    float* gsum = (float*)alloc((size_t)GG * 64 * 4);
    int*   gcnt = (int*)alloc((size_t)GG * 4);
    size_t zbytes = (size_t)((ws + off) - zbase);

    hipMemsetAsync(zbase, 0, zbytes, stream);

    int gblk = (NN + 15) / 16;
    int eblk = (EE + 15) / 16;

    // layer 1 (K = 128)
    hipMemsetAsync(ACCa, 0, accden_bytes, stream);
    k_gemm_dual<128, false><<<gblk, 256, 0, stream>>>(X0, nullptr, nullptr, W1s, W1d, FS, FD);
    k_edge_atomic<<<eblk, 256, 0, stream>>>(src, dst, FS, FD, a1, ACCa, DENa);
    // layer 2 (K = 192): gemm input = ACCa/DENa + b1 (fused finalize)
    hipMemsetAsync(ACCb, 0, accden_bytes, stream);
    k_gemm_dual<192, true><<<gblk, 256, 0, stream>>>(ACCa, DENa, b1, W2s, W2d, FS, FD);
    k_edge_atomic<<<eblk, 256, 0, stream>>>(src, dst, FS, FD, a2, ACCb, DENb);
    // layer 3 (K = 192): gemm input = ACCb/DENb + b2
    hipMemsetAsync(ACCa, 0, accden_bytes, stream);
    k_gemm_dual<192, true><<<gblk, 256, 0, stream>>>(ACCb, DENb, b2, W3s, W3d, FS, FD);
    k_edge_atomic<<<eblk, 256, 0, stream>>>(src, dst, FS, FD, a3, ACCa, DENa);
    // per-graph mean (sorted graph_ids -> contiguous ranges)
    k_graph_mean<<<GG * 4, 256, 0, stream>>>(ACCa, DENa, b3, gid, gsum, gcnt);

    k_head<<<1, 256, 0, stream>>>(gsum, gcnt, p1, p2, p3, Wex, bex, Wpat, bpat,
                                  Wc1, bc1, Wc2, bc2, Wc3, bc3, out);
}

// Round 8
// 716.507 us; speedup vs baseline: 2.7861x; 1.9438x over previous
//
#include <hip/hip_runtime.h>
#include <cstdint>
#include <cstddef>

// Problem constants (fixed by the reference)
#define NN 50000
#define EE 400000
#define FIN 128
#define HH 3
#define DD 64
#define GG 64
#define PP 64
#define HD 192   // H*D

typedef short bf16x8 __attribute__((ext_vector_type(8)));   // 8 bf16 (4 VGPRs)
typedef float f32x4 __attribute__((ext_vector_type(4)));

__device__ inline float wsum(float v) {
#pragma unroll
    for (int m = 32; m > 0; m >>= 1) v += __shfl_xor(v, m, 64);
    return v;
}

// bf16 <-> f32 (RNE)
__device__ inline float bf2f(unsigned short u) {
    union { unsigned int i; float f; } x; x.i = ((unsigned int)u) << 16; return x.f;
}
__device__ inline unsigned short f2bf(float f) {
    union { float f; unsigned int i; } x; x.f = f;
    unsigned int r = x.i + 0x7FFFu + ((x.i >> 16) & 1u);
    return (unsigned short)(r >> 16);
}

// ---------------- CSR build (dst-sorted edge order) ----------------
__global__ void k_count(const int* __restrict__ dst, int* __restrict__ counts) {
    int e = blockIdx.x * 256 + threadIdx.x;
    if (e < EE) atomicAdd(&counts[dst[e]], 1);
}

__global__ void k_scan_block(const int* __restrict__ in, int* __restrict__ out,
                             int* __restrict__ bsums) {
    __shared__ int tmp[1024];
    int tid = threadIdx.x;
    int i = blockIdx.x * 1024 + tid;
    int v = (i < NN) ? in[i] : 0;
    tmp[tid] = v;
    __syncthreads();
    for (int off = 1; off < 1024; off <<= 1) {
        int t = (tid >= off) ? tmp[tid - off] : 0;
        __syncthreads();
        tmp[tid] += t;
        __syncthreads();
    }
    if (i < NN) out[i] = tmp[tid] - v;
    if (tid == 1023) bsums[blockIdx.x] = tmp[1023];
}

__global__ void k_scan_top(int* bsums, int nb) {
    int lane = threadIdx.x;
    int v = (lane < nb) ? bsums[lane] : 0;
    int x = v;
    for (int off = 1; off < 64; off <<= 1) {
        int t = __shfl_up(x, off, 64);
        if (lane >= off) x += t;
    }
    if (lane < nb) bsums[lane] = x - v;
}

__global__ void k_scan_add(int* __restrict__ row_ptr, const int* __restrict__ bsums) {
    int i = blockIdx.x * 1024 + threadIdx.x;
    if (i < NN) row_ptr[i] += bsums[blockIdx.x];
}

__global__ void k_scatter(const int* __restrict__ src, const int* __restrict__ dst,
                          const int* __restrict__ row_ptr, int* __restrict__ cursor,
                          int* __restrict__ csr_src, int* __restrict__ csr_dst) {
    int e = blockIdx.x * 256 + threadIdx.x;
    if (e >= EE) return;
    int v = dst[e];
    int pos = row_ptr[v] + atomicAdd(&cursor[v], 1);
    csr_src[pos] = src[e];
    csr_dst[pos] = v;
}

// ---------------- weight pre-pack into MFMA B-fragment layout ----------------
// WP[((ct*Kc + kc)*64 + lane)*8 + j] = bf16(W[kc*32 + (lane>>4)*8 + j][ct*16 + (lane&15)])
template <int K>
__global__ void k_pack2(const float* __restrict__ Ws, const float* __restrict__ Wd,
                        unsigned short* __restrict__ WPs, unsigned short* __restrict__ WPd) {
    constexpr int Kc = K / 32;
    int total = 12 * Kc * 64;
    int idx = blockIdx.x * 256 + threadIdx.x;
    if (idx >= 2 * total) return;
    const float* W = (idx < total) ? Ws : Wd;
    unsigned short* WP = (idx < total) ? WPs : WPd;
    int id = (idx < total) ? idx : idx - total;
    int lane = id & 63;
    int kc = (id >> 6) % Kc;
    int ct = (id >> 6) / Kc;
    int n = ct * 16 + (lane & 15);
    int kb = kc * 32 + (lane >> 4) * 8;
#pragma unroll
    for (int j = 0; j < 8; j++)
        WP[(size_t)id * 8 + j] = f2bf(W[(size_t)(kb + j) * HD + n]);
}

// ---------------- MFMA GEMM: [N,K]@[K,192] x2 (Ws,Wd); outputs bf16 ------------
// FUSE: input row = ACC[row]/DEN[row] + bias_prev (prev layer's normalize fused)
template <int K, bool FUSE>
__global__ __launch_bounds__(256) void k_gemm_mfma(const float* __restrict__ X,
                                                   const float* __restrict__ DENp,
                                                   const float* __restrict__ bprev,
                                                   const unsigned short* __restrict__ WPs,
                                                   const unsigned short* __restrict__ WPd,
                                                   unsigned short* __restrict__ FS,
                                                   unsigned short* __restrict__ FD) {
    constexpr int Kc = K / 32;
    __shared__ unsigned short xs[16][K + 8];   // +8 bf16 pad: 16B-aligned rows, no 4-way LDS conflicts
    int tid = threadIdx.x;
    int row0 = blockIdx.x * 16;
    for (int idx = tid; idx < 16 * K; idx += 256) {
        int r = idx / K, k = idx - r * K;
        int row = row0 + r;
        float val = 0.f;
        if (row < NN) {
            if (FUSE) {
                float den = DENp[row * 4 + (k >> 6)];
                val = X[(size_t)row * K + k] / fmaxf(den, 1e-9f) + bprev[k];
            } else {
                val = X[(size_t)row * K + k];
            }
        }
        xs[r][k] = f2bf(val);
    }
    __syncthreads();

    int lane = tid & 63, wv = tid >> 6;
    int m = lane & 15, quad = lane >> 4;
    f32x4 acc[6];
#pragma unroll
    for (int t = 0; t < 6; t++) acc[t] = (f32x4){0.f, 0.f, 0.f, 0.f};

    for (int kc = 0; kc < Kc; kc++) {
        bf16x8 a = *(const bf16x8*)&xs[m][kc * 32 + quad * 8];
#pragma unroll
        for (int t = 0; t < 6; t++) {
            int ct = wv * 6 + t;                       // 0..23
            const unsigned short* wp = (ct < 12) ? WPs : WPd;
            int c = (ct < 12) ? ct : ct - 12;
            bf16x8 b = *(const bf16x8*)&wp[(((size_t)c * Kc + kc) * 64 + lane) * 8];
            acc[t] = __builtin_amdgcn_mfma_f32_16x16x32_bf16(a, b, acc[t], 0, 0, 0);
        }
    }
#pragma unroll
    for (int t = 0; t < 6; t++) {
        int ct = wv * 6 + t;
        unsigned short* OUT = (ct < 12) ? FS : FD;
        int c = (ct < 12) ? ct : ct - 12;
#pragma unroll
        for (int r = 0; r < 4; r++) {
            int row = row0 + quad * 4 + r;
            if (row < NN)
                OUT[(size_t)row * HD + c * 16 + m] = f2bf(acc[t][r]);
        }
    }
}

// ---------------- edge-parallel GATv2 on dst-sorted edges + run merge ----------
// One wave per 4 consecutive sorted edges: 24 gathers in flight, 12 interleaved
// reductions, then per-run register merge so each distinct dst gets ONE atomic
// set (avg ~1.5 distinct dst per wave at mean degree 8).
__global__ __launch_bounds__(256) void k_edge_atomic(const int* __restrict__ csr_src,
                                                     const int* __restrict__ csr_dst,
                                                     const unsigned short* __restrict__ FS,
                                                     const unsigned short* __restrict__ FD,
                                                     const float* __restrict__ A,
                                                     float* __restrict__ ACC,
                                                     float* __restrict__ DEN) {
    int wv = threadIdx.x >> 6, lane = threadIdx.x & 63;
    int e0 = blockIdx.x * 16 + wv * 4;
    float a0 = A[lane], a1 = A[64 + lane], a2 = A[128 + lane];

    int u[4], v[4];
    bool ok[4];
#pragma unroll
    for (int i = 0; i < 4; i++) {
        int e = e0 + i;
        ok[i] = e < EE;
        u[i] = ok[i] ? csr_src[e] : 0;
        v[i] = ok[i] ? csr_dst[e] : -1;
    }
    float f[4][3], g[4][3];
#pragma unroll
    for (int i = 0; i < 4; i++) {
        size_t bu = (size_t)u[i] * HD, bv = (size_t)v[i] * HD;
        if (!ok[i]) { bu = 0; bv = 0; }
        f[i][0] = bf2f(FS[bu + lane]);
        f[i][1] = bf2f(FS[bu + 64 + lane]);
        f[i][2] = bf2f(FS[bu + 128 + lane]);
        g[i][0] = bf2f(FD[bv + lane]);
        g[i][1] = bf2f(FD[bv + 64 + lane]);
        g[i][2] = bf2f(FD[bv + 128 + lane]);
    }
    float w[4][3];
#pragma unroll
    for (int i = 0; i < 4; i++) {
        float s0 = f[i][0] + g[i][0]; s0 = s0 > 0.f ? s0 : 0.2f * s0;
        float s1 = f[i][1] + g[i][1]; s1 = s1 > 0.f ? s1 : 0.2f * s1;
        float s2 = f[i][2] + g[i][2]; s2 = s2 > 0.f ? s2 : 0.2f * s2;
        w[i][0] = s0 * a0; w[i][1] = s1 * a1; w[i][2] = s2 * a2;
    }
#pragma unroll
    for (int i = 0; i < 4; i++)
#pragma unroll
        for (int h = 0; h < 3; h++) w[i][h] = wsum(w[i][h]);
#pragma unroll
    for (int i = 0; i < 4; i++)
#pragma unroll
        for (int h = 0; h < 3; h++) w[i][h] = __expf(w[i][h]);

    // run-merge: consecutive sorted edges sharing dst -> single atomic flush
    float r0 = 0.f, r1 = 0.f, r2 = 0.f, d0 = 0.f, d1 = 0.f, d2 = 0.f;
    int vcur = -1;
#pragma unroll
    for (int i = 0; i < 4; i++) {
        if (!ok[i]) continue;
        if (v[i] != vcur) {
            if (vcur >= 0) {
                size_t bv = (size_t)vcur * HD;
                atomicAdd(&ACC[bv + lane], r0);
                atomicAdd(&ACC[bv + 64 + lane], r1);
                atomicAdd(&ACC[bv + 128 + lane], r2);
                if (lane < 3) {
                    float dv = lane == 0 ? d0 : (lane == 1 ? d1 : d2);
                    atomicAdd(&DEN[vcur * 4 + lane], dv);
                }
            }
            vcur = v[i];
            r0 = r1 = r2 = 0.f; d0 = d1 = d2 = 0.f;
        }
        r0 += w[i][0] * f[i][0]; d0 += w[i][0];
        r1 += w[i][1] * f[i][1]; d1 += w[i][1];
        r2 += w[i][2] * f[i][2]; d2 += w[i][2];
    }
    if (vcur >= 0) {
        size_t bv = (size_t)vcur * HD;
        atomicAdd(&ACC[bv + lane], r0);
        atomicAdd(&ACC[bv + 64 + lane], r1);
        atomicAdd(&ACC[bv + 128 + lane], r2);
        if (lane < 3) {
            float dv = lane == 0 ? d0 : (lane == 1 ? d1 : d2);
            atomicAdd(&DEN[vcur * 4 + lane], dv);
        }
    }
}

// ---------------- final: per-graph mean (graph_ids SORTED -> binary search) -----
__global__ __launch_bounds__(256) void k_graph_mean(const float* __restrict__ ACC,
                                                    const float* __restrict__ DEN,
                                                    const float* __restrict__ bias,
                                                    const int* __restrict__ gids,
                                                    float* __restrict__ gsum,
                                                    int* __restrict__ gcnt) {
    int g = blockIdx.x >> 2, q = blockIdx.x & 3;
    int lo, hi;
    {
        int a = 0, b = NN;
        while (a < b) { int m = (a + b) >> 1; if (gids[m] < g) a = m + 1; else b = m; }
        lo = a;
        b = NN;
        while (a < b) { int m = (a + b) >> 1; if (gids[m] < g + 1) a = m + 1; else b = m; }
        hi = a;
    }
    int len = hi - lo;
    int qlen = (len + 3) >> 2;
    int s = lo + q * qlen;
    int e = s + qlen; if (e > hi) e = hi;
    int lane = threadIdx.x & 63, wv = threadIdx.x >> 6;

    float acc = 0.f;
    for (int v = s + wv; v < e; v += 4) {
        float r = 0.f;
#pragma unroll
        for (int h = 0; h < 3; h++) {
            float den = DEN[v * 4 + h];
            r += ACC[(size_t)v * HD + h * 64 + lane] / fmaxf(den, 1e-9f) + bias[h * 64 + lane];
        }
        acc += r * (1.f / 3.f);
    }
    __shared__ float red[4][64];
    red[wv][lane] = acc;
    __syncthreads();
    if (wv == 0) {
        float t = red[0][lane] + red[1][lane] + red[2][lane] + red[3][lane];
        if (e > s) {
            atomicAdd(&gsum[g * 64 + lane], t);
            if (lane == 0) atomicAdd(&gcnt[g], e - s);
        }
    }
}

// ---------------- head: graph mean + pattern branch + classifier ----------------
__global__ __launch_bounds__(256) void k_head(const float* __restrict__ gsum, const int* __restrict__ gcnt,
                                              const float* __restrict__ p1, const float* __restrict__ p2,
                                              const float* __restrict__ p3,
                                              const float* __restrict__ Wex, const float* __restrict__ bex,
                                              const float* __restrict__ Wpat, const float* __restrict__ bpat,
                                              const float* __restrict__ Wc1, const float* __restrict__ bc1,
                                              const float* __restrict__ Wc2, const float* __restrict__ bc2,
                                              const float* __restrict__ Wc3, const float* __restrict__ bc3,
                                              float* __restrict__ out) {
    __shared__ float EX[64 * 96];    // reused for T1 (4096) + T2 (2048)
    __shared__ float XC[64 * 128];
    int tid = threadIdx.x;
    for (int idx = tid; idx < 64 * 96; idx += 256) {
        int g = idx / 96, j = idx - g * 96;
        const float* pp = (j < 32) ? p1 : ((j < 64) ? p2 : p3);
        int jj = j & 31;
        float acc = bex[jj];
        for (int k = 0; k < 64; k++) acc += pp[g * 64 + k] * Wex[k * 32 + jj];
        EX[idx] = acc;
    }
    for (int idx = tid; idx < 64 * 64; idx += 256) {
        int g = idx >> 6, d = idx & 63;
        float c = (float)gcnt[g];
        XC[g * 128 + d] = gsum[idx] / fmaxf(c, 1.f);
    }
    __syncthreads();
    for (int idx = tid; idx < 64 * 64; idx += 256) {
        int g = idx >> 6, j = idx & 63;
        float acc = bpat[j];
        for (int k = 0; k < 96; k++) acc += EX[g * 96 + k] * Wpat[k * 64 + j];
        XC[g * 128 + 64 + j] = acc > 0.f ? acc : 0.01f * acc;
    }
    __syncthreads();
    float* T1 = EX;
    for (int idx = tid; idx < 64 * 64; idx += 256) {
        int g = idx >> 6, j = idx & 63;
        float acc = bc1[j];
        for (int k = 0; k < 128; k++) acc += XC[g * 128 + k] * Wc1[k * 64 + j];
        T1[idx] = acc > 0.f ? acc : 0.01f * acc;
    }
    __syncthreads();
    float* T2 = EX + 4096;
    for (int idx = tid; idx < 64 * 32; idx += 256) {
        int g = idx >> 5, j = idx & 31;
        float acc = bc2[j];
        for (int k = 0; k < 64; k++) acc += T1[g * 64 + k] * Wc2[k * 32 + j];
        T2[idx] = acc > 0.f ? acc : 0.01f * acc;
    }
    __syncthreads();
    for (int idx = tid; idx < 64 * 2; idx += 256) {
        int g = idx >> 1, c = idx & 1;
        float acc = bc3[c];
        for (int k = 0; k < 32; k++) acc += T2[g * 32 + k] * Wc3[k * 2 + c];
        out[idx] = acc;
    }
}

extern "C" void kernel_launch(void* const* d_in, const int* in_sizes, int n_in,
                              void* d_out, int out_size, void* d_ws, size_t ws_size,
                              hipStream_t stream) {
    const float* X0  = (const float*)d_in[0];
    const int*   src = (const int*)d_in[1];
    const int*   dst = (const int*)d_in[2];
    const int*   gid = (const int*)d_in[3];
    const float* p1  = (const float*)d_in[4];
    const float* p2  = (const float*)d_in[5];
    const float* p3  = (const float*)d_in[6];
    const float* W1s = (const float*)d_in[7],  *W1d = (const float*)d_in[8];
    const float* a1  = (const float*)d_in[9],  *b1  = (const float*)d_in[10];
    const float* W2s = (const float*)d_in[11], *W2d = (const float*)d_in[12];
    const float* a2  = (const float*)d_in[13], *b2  = (const float*)d_in[14];
    const float* W3s = (const float*)d_in[15], *W3d = (const float*)d_in[16];
    const float* a3  = (const float*)d_in[17], *b3  = (const float*)d_in[18];
    const float* Wex = (const float*)d_in[19], *bex = (const float*)d_in[20];
    const float* Wpat= (const float*)d_in[21], *bpat= (const float*)d_in[22];
    const float* Wc1 = (const float*)d_in[23], *bc1 = (const float*)d_in[24];
    const float* Wc2 = (const float*)d_in[25], *bc2 = (const float*)d_in[26];
    const float* Wc3 = (const float*)d_in[27], *bc3 = (const float*)d_in[28];
    float* out = (float*)d_out;

    char* ws = (char*)d_ws;
    size_t off = 0;
    auto alloc = [&](size_t bytes) -> char* {
        char* p = ws + off;
        off = (off + bytes + 255) & ~(size_t)255;
        return p;
    };
    unsigned short* FS = (unsigned short*)alloc((size_t)NN * HD * 2);  // bf16
    unsigned short* FD = (unsigned short*)alloc((size_t)NN * HD * 2);  // bf16
    float* ACCa = (float*)alloc((size_t)NN * HD * 4);
    float* DENa = (float*)alloc((size_t)NN * 4 * 4);
    float* ACCb = (float*)alloc((size_t)NN * HD * 4);
    float* DENb = (float*)alloc((size_t)NN * 4 * 4);
    size_t accden_bytes = (size_t)((char*)DENa - (char*)ACCa) + (size_t)NN * 4 * 4;
    unsigned short* WPs = (unsigned short*)alloc((size_t)192 * 192 * 2);
    unsigned short* WPd = (unsigned short*)alloc((size_t)192 * 192 * 2);
    int* row_ptr = (int*)alloc((size_t)(NN + 1) * 4);
    int* csr_src = (int*)alloc((size_t)EE * 4);
    int* csr_dst = (int*)alloc((size_t)EE * 4);
    int* bsums   = (int*)alloc(64 * 4);
    // zeroed region: counts | cursor | gsum | gcnt
    char* zbase = ws + off;
    int*   counts = (int*)alloc((size_t)NN * 4);
    int*   cursor = (int*)alloc((size_t)NN * 4);
    float* gsum   = (float*)alloc((size_t)GG * 64 * 4);
    int*   gcnt   = (int*)alloc((size_t)GG * 4);
    size_t zbytes = (size_t)((ws + off) - zbase);

    hipMemsetAsync(zbase, 0, zbytes, stream);

    int ebl = (EE + 255) / 256;
    int nb  = (NN + 1023) / 1024;
    k_count<<<ebl, 256, 0, stream>>>(dst, counts);
    k_scan_block<<<nb, 1024, 0, stream>>>(counts, row_ptr, bsums);
    k_scan_top<<<1, 64, 0, stream>>>(bsums, nb);
    k_scan_add<<<nb, 1024, 0, stream>>>(row_ptr, bsums);
    k_scatter<<<ebl, 256, 0, stream>>>(src, dst, row_ptr, cursor, csr_src, csr_dst);

    int gblk = (NN + 15) / 16;
    int eblk = (EE + 15) / 16;
    int pblk128 = (2 * 12 * 4 * 64 + 255) / 256;
    int pblk192 = (2 * 12 * 6 * 64 + 255) / 256;

    // layer 1 (K = 128)
    hipMemsetAsync(ACCa, 0, accden_bytes, stream);
    k_pack2<128><<<pblk128, 256, 0, stream>>>(W1s, W1d, WPs, WPd);
    k_gemm_mfma<128, false><<<gblk, 256, 0, stream>>>(X0, nullptr, nullptr, WPs, WPd, FS, FD);
    k_edge_atomic<<<eblk, 256, 0, stream>>>(csr_src, csr_dst, FS, FD, a1, ACCa, DENa);
    // layer 2 (K = 192): gemm input = ACCa/DENa + b1 (fused finalize)
    hipMemsetAsync(ACCb, 0, accden_bytes, stream);
    k_pack2<192><<<pblk192, 256, 0, stream>>>(W2s, W2d, WPs, WPd);
    k_gemm_mfma<192, true><<<gblk, 256, 0, stream>>>(ACCa, DENa, b1, WPs, WPd, FS, FD);
    k_edge_atomic<<<eblk, 256, 0, stream>>>(csr_src, csr_dst, FS, FD, a2, ACCb, DENb);
    // layer 3 (K = 192): gemm input = ACCb/DENb + b2
    k_pack2<192><<<pblk192, 256, 0, stream>>>(W3s, W3d, WPs, WPd);
    hipMemsetAsync(ACCa, 0, accden_bytes, stream);
    k_gemm_mfma<192, true><<<gblk, 256, 0, stream>>>(ACCb, DENb, b2, WPs, WPd, FS, FD);
    k_edge_atomic<<<eblk, 256, 0, stream>>>(csr_src, csr_dst, FS, FD, a3, ACCa, DENa);
    // per-graph mean (sorted graph_ids -> contiguous ranges)
    k_graph_mean<<<GG * 4, 256, 0, stream>>>(ACCa, DENa, b3, gid, gsum, gcnt);

    k_head<<<1, 256, 0, stream>>>(gsum, gcnt, p1, p2, p3, Wex, bex, Wpat, bpat,
                                  Wc1, bc1, Wc2, bc2, Wc3, bc3, out);
}

// Round 9
// 614.058 us; speedup vs baseline: 3.2509x; 1.1668x over previous
//
#include <hip/hip_runtime.h>
#include <cstdint>
#include <cstddef>

// Problem constants (fixed by the reference)
#define NN 50000
#define EE 400000
#define FIN 128
#define HH 3
#define DD 64
#define GG 64
#define PP 64
#define HD 192   // H*D

typedef short bf16x8 __attribute__((ext_vector_type(8)));   // 8 bf16 (4 VGPRs)
typedef float f32x4 __attribute__((ext_vector_type(4)));

__device__ inline float wsum(float v) {
#pragma unroll
    for (int m = 32; m > 0; m >>= 1) v += __shfl_xor(v, m, 64);
    return v;
}

// bf16 <-> f32 (RNE)
__device__ inline float bf2f(unsigned short u) {
    union { unsigned int i; float f; } x; x.i = ((unsigned int)u) << 16; return x.f;
}
__device__ inline unsigned short f2bf(float f) {
    union { float f; unsigned int i; } x; x.f = f;
    unsigned int r = x.i + 0x7FFFu + ((x.i >> 16) & 1u);
    return (unsigned short)(r >> 16);
}

// ---------------- CSR build (dst-sorted edge order) ----------------
__global__ void k_count(const int* __restrict__ dst, int* __restrict__ counts) {
    int e = blockIdx.x * 256 + threadIdx.x;
    if (e < EE) atomicAdd(&counts[dst[e]], 1);
}

__global__ void k_scan_block(const int* __restrict__ in, int* __restrict__ out,
                             int* __restrict__ bsums) {
    __shared__ int tmp[1024];
    int tid = threadIdx.x;
    int i = blockIdx.x * 1024 + tid;
    int v = (i < NN) ? in[i] : 0;
    tmp[tid] = v;
    __syncthreads();
    for (int off = 1; off < 1024; off <<= 1) {
        int t = (tid >= off) ? tmp[tid - off] : 0;
        __syncthreads();
        tmp[tid] += t;
        __syncthreads();
    }
    if (i < NN) out[i] = tmp[tid] - v;
    if (tid == 1023) bsums[blockIdx.x] = tmp[1023];
}

__global__ void k_scan_top(int* bsums, int nb) {
    int lane = threadIdx.x;
    int v = (lane < nb) ? bsums[lane] : 0;
    int x = v;
    for (int off = 1; off < 64; off <<= 1) {
        int t = __shfl_up(x, off, 64);
        if (lane >= off) x += t;
    }
    if (lane < nb) bsums[lane] = x - v;
}

__global__ void k_scan_add(int* __restrict__ row_ptr, const int* __restrict__ bsums) {
    int i = blockIdx.x * 1024 + threadIdx.x;
    if (i < NN) row_ptr[i] += bsums[blockIdx.x];
}

__global__ void k_scatter(const int* __restrict__ src, const int* __restrict__ dst,
                          const int* __restrict__ row_ptr, int* __restrict__ cursor,
                          int* __restrict__ csr_src, int* __restrict__ csr_dst) {
    int e = blockIdx.x * 256 + threadIdx.x;
    if (e >= EE) return;
    int v = dst[e];
    int pos = row_ptr[v] + atomicAdd(&cursor[v], 1);
    csr_src[pos] = src[e];
    csr_dst[pos] = v;
}

// ---------------- weight pre-pack: ALL 6 matrices, one dispatch ----------------
// WP[((ct*Kc + kc)*64 + lane)*8 + j] = bf16(W[kc*32 + (lane>>4)*8 + j][ct*16 + (lane&15)])
__device__ inline void pack_one(const float* __restrict__ W, unsigned short* __restrict__ WP,
                                int id, int Kc) {
    int lane = id & 63;
    int kc = (id >> 6) % Kc;
    int ct = (id >> 6) / Kc;
    int n = ct * 16 + (lane & 15);
    int kb = kc * 32 + (lane >> 4) * 8;
#pragma unroll
    for (int j = 0; j < 8; j++)
        WP[(size_t)id * 8 + j] = f2bf(W[(size_t)(kb + j) * HD + n]);
}

#define IDS128 (12 * 4 * 64)   // 3072
#define IDS192 (12 * 6 * 64)   // 4608
__global__ void k_pack_all(const float* W1s, const float* W1d,
                           const float* W2s, const float* W2d,
                           const float* W3s, const float* W3d,
                           unsigned short* P1s, unsigned short* P1d,
                           unsigned short* P2s, unsigned short* P2d,
                           unsigned short* P3s, unsigned short* P3d) {
    int idx = blockIdx.x * 256 + threadIdx.x;
    if (idx < IDS128) { pack_one(W1s, P1s, idx, 4); return; }
    idx -= IDS128;
    if (idx < IDS128) { pack_one(W1d, P1d, idx, 4); return; }
    idx -= IDS128;
    if (idx < IDS192) { pack_one(W2s, P2s, idx, 6); return; }
    idx -= IDS192;
    if (idx < IDS192) { pack_one(W2d, P2d, idx, 6); return; }
    idx -= IDS192;
    if (idx < IDS192) { pack_one(W3s, P3s, idx, 6); return; }
    idx -= IDS192;
    if (idx < IDS192) { pack_one(W3d, P3d, idx, 6); return; }
}

// ---------------- MFMA GEMM: [N,K]@[K,192] x2 (Ws,Wd); outputs bf16 ------------
// FUSE: input row = ACC[row]/DEN[row] + bias_prev (prev layer's normalize fused).
// Epilogue routes C through LDS -> contiguous 16B stores (50000 = 16*3125: no guards).
template <int K, bool FUSE>
__global__ __launch_bounds__(256) void k_gemm_mfma(const float* __restrict__ X,
                                                   const float* __restrict__ DENp,
                                                   const float* __restrict__ bprev,
                                                   const unsigned short* __restrict__ WPs,
                                                   const unsigned short* __restrict__ WPd,
                                                   unsigned short* __restrict__ FS,
                                                   unsigned short* __restrict__ FD) {
    constexpr int Kc = K / 32;
    __shared__ unsigned short xs[16][K + 8];
    __shared__ unsigned short cs[16][392];   // [row][0..191]=FS cols, [192..383]=FD cols
    int tid = threadIdx.x;
    int row0 = blockIdx.x * 16;
    for (int idx = tid; idx < 16 * K; idx += 256) {
        int r = idx / K, k = idx - r * K;
        int row = row0 + r;
        float val;
        if (FUSE) {
            float den = DENp[row * 4 + (k >> 6)];
            val = X[(size_t)row * K + k] / fmaxf(den, 1e-9f) + bprev[k];
        } else {
            val = X[(size_t)row * K + k];
        }
        xs[r][k] = f2bf(val);
    }
    __syncthreads();

    int lane = tid & 63, wv = tid >> 6;
    int m = lane & 15, quad = lane >> 4;
    f32x4 acc[6];
#pragma unroll
    for (int t = 0; t < 6; t++) acc[t] = (f32x4){0.f, 0.f, 0.f, 0.f};

    for (int kc = 0; kc < Kc; kc++) {
        bf16x8 a = *(const bf16x8*)&xs[m][kc * 32 + quad * 8];
#pragma unroll
        for (int t = 0; t < 6; t++) {
            int ct = wv * 6 + t;                       // 0..23
            const unsigned short* wp = (ct < 12) ? WPs : WPd;
            int c = (ct < 12) ? ct : ct - 12;
            bf16x8 b = *(const bf16x8*)&wp[(((size_t)c * Kc + kc) * 64 + lane) * 8];
            acc[t] = __builtin_amdgcn_mfma_f32_16x16x32_bf16(a, b, acc[t], 0, 0, 0);
        }
    }
    // C -> LDS (2B writes, <=2-way conflicts: free)
#pragma unroll
    for (int t = 0; t < 6; t++) {
        int ct = wv * 6 + t;
#pragma unroll
        for (int r = 0; r < 4; r++)
            cs[quad * 4 + r][ct * 16 + m] = f2bf(acc[t][r]);
    }
    __syncthreads();
    // LDS -> global, 16B chunks: 768 chunks of 8 shorts
#pragma unroll
    for (int it = 0; it < 3; it++) {
        int c = tid + it * 256;
        int hm = c >> 8 >= 0 ? (c / 384) : 0;          // 0=FS, 1=FD
        int cc = c - hm * 384;
        int row = cc / 24, ch = cc - row * 24;
        unsigned short* OUT = hm ? FD : FS;
        *(bf16x8*)&OUT[(size_t)(row0 + row) * HD + ch * 8] =
            *(const bf16x8*)&cs[row][hm * 192 + ch * 8];
    }
}

// ---------------- edge-parallel GATv2 on dst-sorted edges + run merge ----------
// One wave per 8 consecutive sorted edges (EE = 32*12500: no bounds checks).
// 48 gathers in flight, 24 interleaved reductions, per-run register merge ->
// one atomic set per distinct dst.
#define ECH 8
__global__ __launch_bounds__(256) void k_edge_atomic(const int* __restrict__ csr_src,
                                                     const int* __restrict__ csr_dst,
                                                     const unsigned short* __restrict__ FS,
                                                     const unsigned short* __restrict__ FD,
                                                     const float* __restrict__ A,
                                                     float* __restrict__ ACC,
                                                     float* __restrict__ DEN) {
    int wv = threadIdx.x >> 6, lane = threadIdx.x & 63;
    int e0 = blockIdx.x * (4 * ECH) + wv * ECH;
    float a0 = A[lane], a1 = A[64 + lane], a2 = A[128 + lane];

    int u[ECH], v[ECH];
#pragma unroll
    for (int i = 0; i < ECH; i++) {
        u[i] = csr_src[e0 + i];
        v[i] = csr_dst[e0 + i];
    }
    float f[ECH][3], g[ECH][3];
#pragma unroll
    for (int i = 0; i < ECH; i++) {
        size_t bu = (size_t)u[i] * HD, bv = (size_t)v[i] * HD;
        f[i][0] = bf2f(FS[bu + lane]);
        f[i][1] = bf2f(FS[bu + 64 + lane]);
        f[i][2] = bf2f(FS[bu + 128 + lane]);
        g[i][0] = bf2f(FD[bv + lane]);
        g[i][1] = bf2f(FD[bv + 64 + lane]);
        g[i][2] = bf2f(FD[bv + 128 + lane]);
    }
    float w[ECH][3];
#pragma unroll
    for (int i = 0; i < ECH; i++) {
        float s0 = f[i][0] + g[i][0]; s0 = s0 > 0.f ? s0 : 0.2f * s0;
        float s1 = f[i][1] + g[i][1]; s1 = s1 > 0.f ? s1 : 0.2f * s1;
        float s2 = f[i][2] + g[i][2]; s2 = s2 > 0.f ? s2 : 0.2f * s2;
        w[i][0] = s0 * a0; w[i][1] = s1 * a1; w[i][2] = s2 * a2;
    }
#pragma unroll
    for (int i = 0; i < ECH; i++)
#pragma unroll
        for (int h = 0; h < 3; h++) w[i][h] = wsum(w[i][h]);
#pragma unroll
    for (int i = 0; i < ECH; i++)
#pragma unroll
        for (int h = 0; h < 3; h++) w[i][h] = __expf(w[i][h]);

    // run-merge: consecutive sorted edges sharing dst -> single atomic flush
    float r0 = 0.f, r1 = 0.f, r2 = 0.f, d0 = 0.f, d1 = 0.f, d2 = 0.f;
    int vcur = v[0];
#pragma unroll
    for (int i = 0; i < ECH; i++) {
        if (v[i] != vcur) {
            size_t bv = (size_t)vcur * HD;
            atomicAdd(&ACC[bv + lane], r0);
            atomicAdd(&ACC[bv + 64 + lane], r1);
            atomicAdd(&ACC[bv + 128 + lane], r2);
            if (lane < 3) {
                float dv = lane == 0 ? d0 : (lane == 1 ? d1 : d2);
                atomicAdd(&DEN[vcur * 4 + lane], dv);
            }
            vcur = v[i];
            r0 = r1 = r2 = 0.f; d0 = d1 = d2 = 0.f;
        }
        r0 += w[i][0] * f[i][0]; d0 += w[i][0];
        r1 += w[i][1] * f[i][1]; d1 += w[i][1];
        r2 += w[i][2] * f[i][2]; d2 += w[i][2];
    }
    {
        size_t bv = (size_t)vcur * HD;
        atomicAdd(&ACC[bv + lane], r0);
        atomicAdd(&ACC[bv + 64 + lane], r1);
        atomicAdd(&ACC[bv + 128 + lane], r2);
        if (lane < 3) {
            float dv = lane == 0 ? d0 : (lane == 1 ? d1 : d2);
            atomicAdd(&DEN[vcur * 4 + lane], dv);
        }
    }
}

// ---------------- final: per-graph mean (graph_ids SORTED -> binary search) -----
__global__ __launch_bounds__(256) void k_graph_mean(const float* __restrict__ ACC,
                                                    const float* __restrict__ DEN,
                                                    const float* __restrict__ bias,
                                                    const int* __restrict__ gids,
                                                    float* __restrict__ gsum,
                                                    int* __restrict__ gcnt) {
    int g = blockIdx.x >> 2, q = blockIdx.x & 3;
    int lo, hi;
    {
        int a = 0, b = NN;
        while (a < b) { int m = (a + b) >> 1; if (gids[m] < g) a = m + 1; else b = m; }
        lo = a;
        b = NN;
        while (a < b) { int m = (a + b) >> 1; if (gids[m] < g + 1) a = m + 1; else b = m; }
        hi = a;
    }
    int len = hi - lo;
    int qlen = (len + 3) >> 2;
    int s = lo + q * qlen;
    int e = s + qlen; if (e > hi) e = hi;
    int lane = threadIdx.x & 63, wv = threadIdx.x >> 6;

    float acc = 0.f;
    for (int v = s + wv; v < e; v += 4) {
        float r = 0.f;
#pragma unroll
        for (int h = 0; h < 3; h++) {
            float den = DEN[v * 4 + h];
            r += ACC[(size_t)v * HD + h * 64 + lane] / fmaxf(den, 1e-9f) + bias[h * 64 + lane];
        }
        acc += r * (1.f / 3.f);
    }
    __shared__ float red[4][64];
    red[wv][lane] = acc;
    __syncthreads();
    if (wv == 0) {
        float t = red[0][lane] + red[1][lane] + red[2][lane] + red[3][lane];
        if (e > s) {
            atomicAdd(&gsum[g * 64 + lane], t);
            if (lane == 0) atomicAdd(&gcnt[g], e - s);
        }
    }
}

// ---------------- head: graph mean + pattern branch + classifier ----------------
__global__ __launch_bounds__(256) void k_head(const float* __restrict__ gsum, const int* __restrict__ gcnt,
                                              const float* __restrict__ p1, const float* __restrict__ p2,
                                              const float* __restrict__ p3,
                                              const float* __restrict__ Wex, const float* __restrict__ bex,
                                              const float* __restrict__ Wpat, const float* __restrict__ bpat,
                                              const float* __restrict__ Wc1, const float* __restrict__ bc1,
                                              const float* __restrict__ Wc2, const float* __restrict__ bc2,
                                              const float* __restrict__ Wc3, const float* __restrict__ bc3,
                                              float* __restrict__ out) {
    __shared__ float EX[64 * 96];    // reused for T1 (4096) + T2 (2048)
    __shared__ float XC[64 * 128];
    int tid = threadIdx.x;
    for (int idx = tid; idx < 64 * 96; idx += 256) {
        int g = idx / 96, j = idx - g * 96;
        const float* pp = (j < 32) ? p1 : ((j < 64) ? p2 : p3);
        int jj = j & 31;
        float acc = bex[jj];
        for (int k = 0; k < 64; k++) acc += pp[g * 64 + k] * Wex[k * 32 + jj];
        EX[idx] = acc;
    }
    for (int idx = tid; idx < 64 * 64; idx += 256) {
        int g = idx >> 6, d = idx & 63;
        float c = (float)gcnt[g];
        XC[g * 128 + d] = gsum[idx] / fmaxf(c, 1.f);
    }
    __syncthreads();
    for (int idx = tid; idx < 64 * 64; idx += 256) {
        int g = idx >> 6, j = idx & 63;
        float acc = bpat[j];
        for (int k = 0; k < 96; k++) acc += EX[g * 96 + k] * Wpat[k * 64 + j];
        XC[g * 128 + 64 + j] = acc > 0.f ? acc : 0.01f * acc;
    }
    __syncthreads();
    float* T1 = EX;
    for (int idx = tid; idx < 64 * 64; idx += 256) {
        int g = idx >> 6, j = idx & 63;
        float acc = bc1[j];
        for (int k = 0; k < 128; k++) acc += XC[g * 128 + k] * Wc1[k * 64 + j];
        T1[idx] = acc > 0.f ? acc : 0.01f * acc;
    }
    __syncthreads();
    float* T2 = EX + 4096;
    for (int idx = tid; idx < 64 * 32; idx += 256) {
        int g = idx >> 5, j = idx & 31;
        float acc = bc2[j];
        for (int k = 0; k < 64; k++) acc += T1[g * 64 + k] * Wc2[k * 32 + j];
        T2[idx] = acc > 0.f ? acc : 0.01f * acc;
    }
    __syncthreads();
    for (int idx = tid; idx < 64 * 2; idx += 256) {
        int g = idx >> 1, c = idx & 1;
        float acc = bc3[c];
        for (int k = 0; k < 32; k++) acc += T2[g * 32 + k] * Wc3[k * 2 + c];
        out[idx] = acc;
    }
}

extern "C" void kernel_launch(void* const* d_in, const int* in_sizes, int n_in,
                              void* d_out, int out_size, void* d_ws, size_t ws_size,
                              hipStream_t stream) {
    const float* X0  = (const float*)d_in[0];
    const int*   src = (const int*)d_in[1];
    const int*   dst = (const int*)d_in[2];
    const int*   gid = (const int*)d_in[3];
    const float* p1  = (const float*)d_in[4];
    const float* p2  = (const float*)d_in[5];
    const float* p3  = (const float*)d_in[6];
    const float* W1s = (const float*)d_in[7],  *W1d = (const float*)d_in[8];
    const float* a1  = (const float*)d_in[9],  *b1  = (const float*)d_in[10];
    const float* W2s = (const float*)d_in[11], *W2d = (const float*)d_in[12];
    const float* a2  = (const float*)d_in[13], *b2  = (const float*)d_in[14];
    const float* W3s = (const float*)d_in[15], *W3d = (const float*)d_in[16];
    const float* a3  = (const float*)d_in[17], *b3  = (const float*)d_in[18];
    const float* Wex = (const float*)d_in[19], *bex = (const float*)d_in[20];
    const float* Wpat= (const float*)d_in[21], *bpat= (const float*)d_in[22];
    const float* Wc1 = (const float*)d_in[23], *bc1 = (const float*)d_in[24];
    const float* Wc2 = (const float*)d_in[25], *bc2 = (const float*)d_in[26];
    const float* Wc3 = (const float*)d_in[27], *bc3 = (const float*)d_in[28];
    float* out = (float*)d_out;

    char* ws = (char*)d_ws;
    size_t off = 0;
    auto alloc = [&](size_t bytes) -> char* {
        char* p = ws + off;
        off = (off + bytes + 255) & ~(size_t)255;
        return p;
    };
    unsigned short* FS = (unsigned short*)alloc((size_t)NN * HD * 2);  // bf16
    unsigned short* FD = (unsigned short*)alloc((size_t)NN * HD * 2);  // bf16
    unsigned short* P1s = (unsigned short*)alloc((size_t)192 * 192 * 2);
    unsigned short* P1d = (unsigned short*)alloc((size_t)192 * 192 * 2);
    unsigned short* P2s = (unsigned short*)alloc((size_t)192 * 192 * 2);
    unsigned short* P2d = (unsigned short*)alloc((size_t)192 * 192 * 2);
    unsigned short* P3s = (unsigned short*)alloc((size_t)192 * 192 * 2);
    unsigned short* P3d = (unsigned short*)alloc((size_t)192 * 192 * 2);
    int* row_ptr = (int*)alloc((size_t)(NN + 1) * 4);
    int* csr_src = (int*)alloc((size_t)EE * 4);
    int* csr_dst = (int*)alloc((size_t)EE * 4);
    int* bsums   = (int*)alloc(64 * 4);
    // zeroed region (ONE memset): 3x(ACC|DEN) | counts | cursor | gsum | gcnt
    char* zbase = ws + off;
    float* ACCa = (float*)alloc((size_t)NN * HD * 4);
    float* DENa = (float*)alloc((size_t)NN * 4 * 4);
    float* ACCb = (float*)alloc((size_t)NN * HD * 4);
    float* DENb = (float*)alloc((size_t)NN * 4 * 4);
    float* ACCc = (float*)alloc((size_t)NN * HD * 4);
    float* DENc = (float*)alloc((size_t)NN * 4 * 4);
    int*   counts = (int*)alloc((size_t)NN * 4);
    int*   cursor = (int*)alloc((size_t)NN * 4);
    float* gsum   = (float*)alloc((size_t)GG * 64 * 4);
    int*   gcnt   = (int*)alloc((size_t)GG * 4);
    size_t zbytes = (size_t)((ws + off) - zbase);

    hipMemsetAsync(zbase, 0, zbytes, stream);

    int ebl = (EE + 255) / 256;
    int nb  = (NN + 1023) / 1024;
    k_count<<<ebl, 256, 0, stream>>>(dst, counts);
    k_scan_block<<<nb, 1024, 0, stream>>>(counts, row_ptr, bsums);
    k_scan_top<<<1, 64, 0, stream>>>(bsums, nb);
    k_scan_add<<<nb, 1024, 0, stream>>>(row_ptr, bsums);
    k_scatter<<<ebl, 256, 0, stream>>>(src, dst, row_ptr, cursor, csr_src, csr_dst);
    {
        int total = 2 * IDS128 + 4 * IDS192;
        k_pack_all<<<(total + 255) / 256, 256, 0, stream>>>(W1s, W1d, W2s, W2d, W3s, W3d,
                                                            P1s, P1d, P2s, P2d, P3s, P3d);
    }

    int gblk = NN / 16;                 // 3125, exact
    int eblk = EE / (4 * ECH);          // 12500, exact

    // layer 1 (K = 128)
    k_gemm_mfma<128, false><<<gblk, 256, 0, stream>>>(X0, nullptr, nullptr, P1s, P1d, FS, FD);
    k_edge_atomic<<<eblk, 256, 0, stream>>>(csr_src, csr_dst, FS, FD, a1, ACCa, DENa);
    // layer 2 (K = 192): gemm input = ACCa/DENa + b1 (fused finalize)
    k_gemm_mfma<192, true><<<gblk, 256, 0, stream>>>(ACCa, DENa, b1, P2s, P2d, FS, FD);
    k_edge_atomic<<<eblk, 256, 0, stream>>>(csr_src, csr_dst, FS, FD, a2, ACCb, DENb);
    // layer 3 (K = 192): gemm input = ACCb/DENb + b2
    k_gemm_mfma<192, true><<<gblk, 256, 0, stream>>>(ACCb, DENb, b2, P3s, P3d, FS, FD);
    k_edge_atomic<<<eblk, 256, 0, stream>>>(csr_src, csr_dst, FS, FD, a3, ACCc, DENc);
    // per-graph mean (sorted graph_ids -> contiguous ranges)
    k_graph_mean<<<GG * 4, 256, 0, stream>>>(ACCc, DENc, b3, gid, gsum, gcnt);

    k_head<<<1, 256, 0, stream>>>(gsum, gcnt, p1, p2, p3, Wex, bex, Wpat, bpat,
                                  Wc1, bc1, Wc2, bc2, Wc3, bc3, out);
}

// Round 10
// 542.671 us; speedup vs baseline: 3.6786x; 1.1315x over previous
//
#include <hip/hip_runtime.h>
#include <cstdint>
#include <cstddef>

// Problem constants (fixed by the reference)
#define NN 50000
#define EE 400000
#define FIN 128
#define HH 3
#define DD 64
#define GG 64
#define PP 64
#define HD 192   // H*D

typedef short bf16x8 __attribute__((ext_vector_type(8)));   // 8 bf16 (4 VGPRs)
typedef float f32x4 __attribute__((ext_vector_type(4)));

__device__ inline float wsum(float v) {
#pragma unroll
    for (int m = 32; m > 0; m >>= 1) v += __shfl_xor(v, m, 64);
    return v;
}
__device__ inline int wsumi(int v) {
#pragma unroll
    for (int m = 32; m > 0; m >>= 1) v += __shfl_xor(v, m, 64);
    return v;
}

// bf16 <-> f32 (RNE)
__device__ inline float bf2f(unsigned short u) {
    union { unsigned int i; float f; } x; x.i = ((unsigned int)u) << 16; return x.f;
}
__device__ inline unsigned short f2bf(float f) {
    union { float f; unsigned int i; } x; x.f = f;
    unsigned int r = x.i + 0x7FFFu + ((x.i >> 16) & 1u);
    return (unsigned short)(r >> 16);
}

// ---------------- CSR build (dst-sorted edge order) ----------------
__global__ void k_count(const int* __restrict__ dst, int* __restrict__ counts) {
    int e = blockIdx.x * 256 + threadIdx.x;
    if (e < EE) atomicAdd(&counts[dst[e]], 1);
}

__global__ void k_scan_block(const int* __restrict__ in, int* __restrict__ out,
                             int* __restrict__ bsums) {
    __shared__ int tmp[1024];
    int tid = threadIdx.x;
    int i = blockIdx.x * 1024 + tid;
    int v = (i < NN) ? in[i] : 0;
    tmp[tid] = v;
    __syncthreads();
    for (int off = 1; off < 1024; off <<= 1) {
        int t = (tid >= off) ? tmp[tid - off] : 0;
        __syncthreads();
        tmp[tid] += t;
        __syncthreads();
    }
    if (i < NN) out[i] = tmp[tid] - v;
    if (tid == 1023) bsums[blockIdx.x] = tmp[1023];
}

// fused: each block computes its own bsums-prefix (nb <= 64) then adds it
__global__ void k_scan_add(int* __restrict__ row_ptr, const int* __restrict__ bsums, int nb) {
    __shared__ int sbase;
    int tid = threadIdx.x;
    if (tid < 64) {
        int v = (tid < blockIdx.x) ? bsums[tid] : 0;   // blockIdx.x <= nb <= 64
        v = wsumi(v);
        if (tid == 0) sbase = v;
    }
    __syncthreads();
    int i = blockIdx.x * 1024 + tid;
    if (i < NN) row_ptr[i] += sbase;
}

__global__ void k_scatter(const int* __restrict__ src, const int* __restrict__ dst,
                          const int* __restrict__ row_ptr, int* __restrict__ cursor,
                          int* __restrict__ csr_src, int* __restrict__ csr_dst) {
    int e = blockIdx.x * 256 + threadIdx.x;
    if (e >= EE) return;
    int v = dst[e];
    int pos = row_ptr[v] + atomicAdd(&cursor[v], 1);
    csr_src[pos] = src[e];
    csr_dst[pos] = v;
}

// ---------------- weight pre-pack: ALL 6 matrices, one dispatch ----------------
__device__ inline void pack_one(const float* __restrict__ W, unsigned short* __restrict__ WP,
                                int id, int Kc) {
    int lane = id & 63;
    int kc = (id >> 6) % Kc;
    int ct = (id >> 6) / Kc;
    int n = ct * 16 + (lane & 15);
    int kb = kc * 32 + (lane >> 4) * 8;
#pragma unroll
    for (int j = 0; j < 8; j++)
        WP[(size_t)id * 8 + j] = f2bf(W[(size_t)(kb + j) * HD + n]);
}

#define IDS128 (12 * 4 * 64)   // 3072
#define IDS192 (12 * 6 * 64)   // 4608
__global__ void k_pack_all(const float* W1s, const float* W1d,
                           const float* W2s, const float* W2d,
                           const float* W3s, const float* W3d,
                           unsigned short* P1s, unsigned short* P1d,
                           unsigned short* P2s, unsigned short* P2d,
                           unsigned short* P3s, unsigned short* P3d) {
    int idx = blockIdx.x * 256 + threadIdx.x;
    if (idx < IDS128) { pack_one(W1s, P1s, idx, 4); return; }
    idx -= IDS128;
    if (idx < IDS128) { pack_one(W1d, P1d, idx, 4); return; }
    idx -= IDS128;
    if (idx < IDS192) { pack_one(W2s, P2s, idx, 6); return; }
    idx -= IDS192;
    if (idx < IDS192) { pack_one(W2d, P2d, idx, 6); return; }
    idx -= IDS192;
    if (idx < IDS192) { pack_one(W3s, P3s, idx, 6); return; }
    idx -= IDS192;
    if (idx < IDS192) { pack_one(W3d, P3d, idx, 6); return; }
}

// ---------------- MFMA GEMM: [N,K]@[K,192] x2 (Ws,Wd); outputs bf16 ------------
template <int K, bool FUSE>
__global__ __launch_bounds__(256) void k_gemm_mfma(const float* __restrict__ X,
                                                   const float* __restrict__ DENp,
                                                   const float* __restrict__ bprev,
                                                   const unsigned short* __restrict__ WPs,
                                                   const unsigned short* __restrict__ WPd,
                                                   unsigned short* __restrict__ FS,
                                                   unsigned short* __restrict__ FD) {
    constexpr int Kc = K / 32;
    __shared__ unsigned short xs[16][K + 8];
    __shared__ unsigned short cs[16][392];   // [row][0..191]=FS cols, [192..383]=FD cols
    int tid = threadIdx.x;
    int row0 = blockIdx.x * 16;
    for (int idx = tid; idx < 16 * K; idx += 256) {
        int r = idx / K, k = idx - r * K;
        int row = row0 + r;
        float val;
        if (FUSE) {
            float den = DENp[row * 4 + (k >> 6)];
            val = X[(size_t)row * K + k] / fmaxf(den, 1e-9f) + bprev[k];
        } else {
            val = X[(size_t)row * K + k];
        }
        xs[r][k] = f2bf(val);
    }
    __syncthreads();

    int lane = tid & 63, wv = tid >> 6;
    int m = lane & 15, quad = lane >> 4;
    f32x4 acc[6];
#pragma unroll
    for (int t = 0; t < 6; t++) acc[t] = (f32x4){0.f, 0.f, 0.f, 0.f};

    for (int kc = 0; kc < Kc; kc++) {
        bf16x8 a = *(const bf16x8*)&xs[m][kc * 32 + quad * 8];
#pragma unroll
        for (int t = 0; t < 6; t++) {
            int ct = wv * 6 + t;                       // 0..23
            const unsigned short* wp = (ct < 12) ? WPs : WPd;
            int c = (ct < 12) ? ct : ct - 12;
            bf16x8 b = *(const bf16x8*)&wp[(((size_t)c * Kc + kc) * 64 + lane) * 8];
            acc[t] = __builtin_amdgcn_mfma_f32_16x16x32_bf16(a, b, acc[t], 0, 0, 0);
        }
    }
#pragma unroll
    for (int t = 0; t < 6; t++) {
        int ct = wv * 6 + t;
#pragma unroll
        for (int r = 0; r < 4; r++)
            cs[quad * 4 + r][ct * 16 + m] = f2bf(acc[t][r]);
    }
    __syncthreads();
#pragma unroll
    for (int it = 0; it < 3; it++) {
        int c = tid + it * 256;
        int hm = c / 384;                              // 0=FS, 1=FD
        int cc = c - hm * 384;
        int row = cc / 24, ch = cc - row * 24;
        unsigned short* OUT = hm ? FD : FS;
        *(bf16x8*)&OUT[(size_t)(row0 + row) * HD + ch * 8] =
            *(const bf16x8*)&cs[row][hm * 192 + ch * 8];
    }
}

// ---------------- edge-parallel GATv2 on dst-sorted edges + run merge ----------
#define ECH 8
__global__ __launch_bounds__(256) void k_edge_atomic(const int* __restrict__ csr_src,
                                                     const int* __restrict__ csr_dst,
                                                     const unsigned short* __restrict__ FS,
                                                     const unsigned short* __restrict__ FD,
                                                     const float* __restrict__ A,
                                                     float* __restrict__ ACC,
                                                     float* __restrict__ DEN) {
    int wv = threadIdx.x >> 6, lane = threadIdx.x & 63;
    int e0 = blockIdx.x * (4 * ECH) + wv * ECH;
    float a0 = A[lane], a1 = A[64 + lane], a2 = A[128 + lane];

    int u[ECH], v[ECH];
#pragma unroll
    for (int i = 0; i < ECH; i++) {
        u[i] = csr_src[e0 + i];
        v[i] = csr_dst[e0 + i];
    }
    float f[ECH][3], g[ECH][3];
#pragma unroll
    for (int i = 0; i < ECH; i++) {
        size_t bu = (size_t)u[i] * HD, bv = (size_t)v[i] * HD;
        f[i][0] = bf2f(FS[bu + lane]);
        f[i][1] = bf2f(FS[bu + 64 + lane]);
        f[i][2] = bf2f(FS[bu + 128 + lane]);
        g[i][0] = bf2f(FD[bv + lane]);
        g[i][1] = bf2f(FD[bv + 64 + lane]);
        g[i][2] = bf2f(FD[bv + 128 + lane]);
    }
    float w[ECH][3];
#pragma unroll
    for (int i = 0; i < ECH; i++) {
        float s0 = f[i][0] + g[i][0]; s0 = s0 > 0.f ? s0 : 0.2f * s0;
        float s1 = f[i][1] + g[i][1]; s1 = s1 > 0.f ? s1 : 0.2f * s1;
        float s2 = f[i][2] + g[i][2]; s2 = s2 > 0.f ? s2 : 0.2f * s2;
        w[i][0] = s0 * a0; w[i][1] = s1 * a1; w[i][2] = s2 * a2;
    }
#pragma unroll
    for (int i = 0; i < ECH; i++)
#pragma unroll
        for (int h = 0; h < 3; h++) w[i][h] = wsum(w[i][h]);
#pragma unroll
    for (int i = 0; i < ECH; i++)
#pragma unroll
        for (int h = 0; h < 3; h++) w[i][h] = __expf(w[i][h]);

    // run-merge: consecutive sorted edges sharing dst -> single atomic flush
    float r0 = 0.f, r1 = 0.f, r2 = 0.f, d0 = 0.f, d1 = 0.f, d2 = 0.f;
    int vcur = v[0];
#pragma unroll
    for (int i = 0; i < ECH; i++) {
        if (v[i] != vcur) {
            size_t bv = (size_t)vcur * HD;
            atomicAdd(&ACC[bv + lane], r0);
            atomicAdd(&ACC[bv + 64 + lane], r1);
            atomicAdd(&ACC[bv + 128 + lane], r2);
            if (lane < 3) {
                float dv = lane == 0 ? d0 : (lane == 1 ? d1 : d2);
                atomicAdd(&DEN[vcur * 4 + lane], dv);
            }
            vcur = v[i];
            r0 = r1 = r2 = 0.f; d0 = d1 = d2 = 0.f;
        }
        r0 += w[i][0] * f[i][0]; d0 += w[i][0];
        r1 += w[i][1] * f[i][1]; d1 += w[i][1];
        r2 += w[i][2] * f[i][2]; d2 += w[i][2];
    }
    {
        size_t bv = (size_t)vcur * HD;
        atomicAdd(&ACC[bv + lane], r0);
        atomicAdd(&ACC[bv + 64 + lane], r1);
        atomicAdd(&ACC[bv + 128 + lane], r2);
        if (lane < 3) {
            float dv = lane == 0 ? d0 : (lane == 1 ? d1 : d2);
            atomicAdd(&DEN[vcur * 4 + lane], dv);
        }
    }
}

// ---------------- final: per-graph mean (graph_ids SORTED -> binary search) -----
__global__ __launch_bounds__(256) void k_graph_mean(const float* __restrict__ ACC,
                                                    const float* __restrict__ DEN,
                                                    const float* __restrict__ bias,
                                                    const int* __restrict__ gids,
                                                    float* __restrict__ gsum,
                                                    int* __restrict__ gcnt) {
    int g = blockIdx.x >> 2, q = blockIdx.x & 3;
    int lo, hi;
    {
        int a = 0, b = NN;
        while (a < b) { int m = (a + b) >> 1; if (gids[m] < g) a = m + 1; else b = m; }
        lo = a;
        b = NN;
        while (a < b) { int m = (a + b) >> 1; if (gids[m] < g + 1) a = m + 1; else b = m; }
        hi = a;
    }
    int len = hi - lo;
    int qlen = (len + 3) >> 2;
    int s = lo + q * qlen;
    int e = s + qlen; if (e > hi) e = hi;
    int lane = threadIdx.x & 63, wv = threadIdx.x >> 6;

    float acc = 0.f;
    for (int v = s + wv; v < e; v += 4) {
        float r = 0.f;
#pragma unroll
        for (int h = 0; h < 3; h++) {
            float den = DEN[v * 4 + h];
            r += ACC[(size_t)v * HD + h * 64 + lane] / fmaxf(den, 1e-9f) + bias[h * 64 + lane];
        }
        acc += r * (1.f / 3.f);
    }
    __shared__ float red[4][64];
    red[wv][lane] = acc;
    __syncthreads();
    if (wv == 0) {
        float t = red[0][lane] + red[1][lane] + red[2][lane] + red[3][lane];
        if (e > s) {
            atomicAdd(&gsum[g * 64 + lane], t);
            if (lane == 0) atomicAdd(&gcnt[g], e - s);
        }
    }
}

// ---------------- head: one block PER GRAPH (64 blocks) ----------------
__global__ __launch_bounds__(128) void k_head(const float* __restrict__ gsum, const int* __restrict__ gcnt,
                                              const float* __restrict__ p1, const float* __restrict__ p2,
                                              const float* __restrict__ p3,
                                              const float* __restrict__ Wex, const float* __restrict__ bex,
                                              const float* __restrict__ Wpat, const float* __restrict__ bpat,
                                              const float* __restrict__ Wc1, const float* __restrict__ bc1,
                                              const float* __restrict__ Wc2, const float* __restrict__ bc2,
                                              const float* __restrict__ Wc3, const float* __restrict__ bc3,
                                              float* __restrict__ out) {
    int g = blockIdx.x;
    int tid = threadIdx.x;
    __shared__ float pbuf[192];   // p1|p2|p3 row for this graph
    __shared__ float ex[96], xc[128], t1[64], t2[32];

    if (tid < 64)       pbuf[tid] = p1[g * 64 + tid];
    else if (tid < 128) pbuf[tid] = p2[g * 64 + tid - 64];
    if (tid < 64)       pbuf[128 + tid] = p3[g * 64 + tid];
    if (tid >= 64 && tid < 128)
        xc[tid - 64] = gsum[g * 64 + tid - 64] / fmaxf((float)gcnt[g], 1.f);
    __syncthreads();
    if (tid < 96) {
        int jj = tid & 31;
        const float* pp = &pbuf[(tid >> 5) * 64];
        float acc = bex[jj];
        for (int k = 0; k < 64; k++) acc += pp[k] * Wex[k * 32 + jj];
        ex[tid] = acc;
    }
    __syncthreads();
    if (tid < 64) {
        float acc = bpat[tid];
        for (int k = 0; k < 96; k++) acc += ex[k] * Wpat[k * 64 + tid];
        xc[64 + tid] = acc > 0.f ? acc : 0.01f * acc;
    }
    __syncthreads();
    if (tid < 64) {
        float acc = bc1[tid];
        for (int k = 0; k < 128; k++) acc += xc[k] * Wc1[k * 64 + tid];
        t1[tid] = acc > 0.f ? acc : 0.01f * acc;
    }
    __syncthreads();
    if (tid < 32) {
        float acc = bc2[tid];
        for (int k = 0; k < 64; k++) acc += t1[k] * Wc2[k * 32 + tid];
        t2[tid] = acc > 0.f ? acc : 0.01f * acc;
    }
    __syncthreads();
    if (tid < 2) {
        float acc = bc3[tid];
        for (int k = 0; k < 32; k++) acc += t2[k] * Wc3[k * 2 + tid];
        out[g * 2 + tid] = acc;
    }
}

extern "C" void kernel_launch(void* const* d_in, const int* in_sizes, int n_in,
                              void* d_out, int out_size, void* d_ws, size_t ws_size,
                              hipStream_t stream) {
    const float* X0  = (const float*)d_in[0];
    const int*   src = (const int*)d_in[1];
    const int*   dst = (const int*)d_in[2];
    const int*   gid = (const int*)d_in[3];
    const float* p1  = (const float*)d_in[4];
    const float* p2  = (const float*)d_in[5];
    const float* p3  = (const float*)d_in[6];
    const float* W1s = (const float*)d_in[7],  *W1d = (const float*)d_in[8];
    const float* a1  = (const float*)d_in[9],  *b1  = (const float*)d_in[10];
    const float* W2s = (const float*)d_in[11], *W2d = (const float*)d_in[12];
    const float* a2  = (const float*)d_in[13], *b2  = (const float*)d_in[14];
    const float* W3s = (const float*)d_in[15], *W3d = (const float*)d_in[16];
    const float* a3  = (const float*)d_in[17], *b3  = (const float*)d_in[18];
    const float* Wex = (const float*)d_in[19], *bex = (const float*)d_in[20];
    const float* Wpat= (const float*)d_in[21], *bpat= (const float*)d_in[22];
    const float* Wc1 = (const float*)d_in[23], *bc1 = (const float*)d_in[24];
    const float* Wc2 = (const float*)d_in[25], *bc2 = (const float*)d_in[26];
    const float* Wc3 = (const float*)d_in[27], *bc3 = (const float*)d_in[28];
    float* out = (float*)d_out;

    char* ws = (char*)d_ws;
    size_t off = 0;
    auto alloc = [&](size_t bytes) -> char* {
        char* p = ws + off;
        off = (off + bytes + 255) & ~(size_t)255;
        return p;
    };
    unsigned short* FS = (unsigned short*)alloc((size_t)NN * HD * 2);  // bf16
    unsigned short* FD = (unsigned short*)alloc((size_t)NN * HD * 2);  // bf16
    unsigned short* P1s = (unsigned short*)alloc((size_t)192 * 192 * 2);
    unsigned short* P1d = (unsigned short*)alloc((size_t)192 * 192 * 2);
    unsigned short* P2s = (unsigned short*)alloc((size_t)192 * 192 * 2);
    unsigned short* P2d = (unsigned short*)alloc((size_t)192 * 192 * 2);
    unsigned short* P3s = (unsigned short*)alloc((size_t)192 * 192 * 2);
    unsigned short* P3d = (unsigned short*)alloc((size_t)192 * 192 * 2);
    int* row_ptr = (int*)alloc((size_t)(NN + 1) * 4);
    int* csr_src = (int*)alloc((size_t)EE * 4);
    int* csr_dst = (int*)alloc((size_t)EE * 4);
    int* bsums   = (int*)alloc(64 * 4);
    // zeroed region (ONE memset): 3x(ACC|DEN) | counts | cursor | gsum | gcnt
    char* zbase = ws + off;
    float* ACCa = (float*)alloc((size_t)NN * HD * 4);
    float* DENa = (float*)alloc((size_t)NN * 4 * 4);
    float* ACCb = (float*)alloc((size_t)NN * HD * 4);
    float* DENb = (float*)alloc((size_t)NN * 4 * 4);
    float* ACCc = (float*)alloc((size_t)NN * HD * 4);
    float* DENc = (float*)alloc((size_t)NN * 4 * 4);
    int*   counts = (int*)alloc((size_t)NN * 4);
    int*   cursor = (int*)alloc((size_t)NN * 4);
    float* gsum   = (float*)alloc((size_t)GG * 64 * 4);
    int*   gcnt   = (int*)alloc((size_t)GG * 4);
    size_t zbytes = (size_t)((ws + off) - zbase);

    hipMemsetAsync(zbase, 0, zbytes, stream);

    int ebl = (EE + 255) / 256;
    int nb  = (NN + 1023) / 1024;
    k_count<<<ebl, 256, 0, stream>>>(dst, counts);
    k_scan_block<<<nb, 1024, 0, stream>>>(counts, row_ptr, bsums);
    k_scan_add<<<nb, 1024, 0, stream>>>(row_ptr, bsums, nb);
    k_scatter<<<ebl, 256, 0, stream>>>(src, dst, row_ptr, cursor, csr_src, csr_dst);
    {
        int total = 2 * IDS128 + 4 * IDS192;
        k_pack_all<<<(total + 255) / 256, 256, 0, stream>>>(W1s, W1d, W2s, W2d, W3s, W3d,
                                                            P1s, P1d, P2s, P2d, P3s, P3d);
    }

    int gblk = NN / 16;                 // 3125, exact
    int eblk = EE / (4 * ECH);          // 12500, exact

    // layer 1 (K = 128)
    k_gemm_mfma<128, false><<<gblk, 256, 0, stream>>>(X0, nullptr, nullptr, P1s, P1d, FS, FD);
    k_edge_atomic<<<eblk, 256, 0, stream>>>(csr_src, csr_dst, FS, FD, a1, ACCa, DENa);
    // layer 2 (K = 192): gemm input = ACCa/DENa + b1 (fused finalize)
    k_gemm_mfma<192, true><<<gblk, 256, 0, stream>>>(ACCa, DENa, b1, P2s, P2d, FS, FD);
    k_edge_atomic<<<eblk, 256, 0, stream>>>(csr_src, csr_dst, FS, FD, a2, ACCb, DENb);
    // layer 3 (K = 192): gemm input = ACCb/DENb + b2
    k_gemm_mfma<192, true><<<gblk, 256, 0, stream>>>(ACCb, DENb, b2, P3s, P3d, FS, FD);
    k_edge_atomic<<<eblk, 256, 0, stream>>>(csr_src, csr_dst, FS, FD, a3, ACCc, DENc);
    // per-graph mean (sorted graph_ids -> contiguous ranges)
    k_graph_mean<<<GG * 4, 256, 0, stream>>>(ACCc, DENc, b3, gid, gsum, gcnt);

    // head: one block per graph
    k_head<<<GG, 128, 0, stream>>>(gsum, gcnt, p1, p2, p3, Wex, bex, Wpat, bpat,
                                   Wc1, bc1, Wc2, bc2, Wc3, bc3, out);
}